// Round 1
// 806.235 us; speedup vs baseline: 2.0277x; 2.0277x over previous
//
#include <hip/hip_runtime.h>
#include <stdint.h>

// Problem constants
#define KDIM 4096   // IN_DIM
#define NDIM 4096   // OUT_DIM
#define MROWS 8192  // 4*2048
#define SEQ 2048

typedef __attribute__((ext_vector_type(8))) short short8;
typedef __attribute__((ext_vector_type(4))) float f32x4;

__device__ __forceinline__ float bf16_bits_to_f(uint32_t u16) {
  union { uint32_t u; float f; } c; c.u = u16 << 16; return c.f;
}
// Runtime-dual load: flag==1 -> storage is bf16, flag==0 -> f32
__device__ __forceinline__ float dload(const void* p, size_t idx, int flag) {
  if (flag) return bf16_bits_to_f(((const uint16_t*)p)[idx]);
  return ((const float*)p)[idx];
}
__device__ __forceinline__ uint16_t f2b(float f) {  // RNE f32->bf16
  union { float f; uint32_t u; } c; c.f = f;
  uint32_t b = c.u;
  return (uint16_t)((b + 0x7FFFu + ((b >> 16) & 1u)) >> 16);
}
__device__ __forceinline__ uint32_t pk2(float a, float b) {
  return (uint32_t)f2b(a) | ((uint32_t)f2b(b) << 16);
}
// async global->LDS, 16B per lane. LDS dest = wave-uniform base + lane*16.
__device__ __forceinline__ void gld_lds16(const uint16_t* g, uint16_t* l) {
  __builtin_amdgcn_global_load_lds(
      (const __attribute__((address_space(1))) uint32_t*)g,
      (__attribute__((address_space(3))) uint32_t*)l, 16, 0, 0);
}

// ---------------------------------------------------------------------------
// K0: dtype detection (unchanged, verified). flag=1 means bf16 storage.
__global__ void k_detect(const uint16_t* xu, int* flag) {
  int lane = threadIdx.x;  // 64 threads, 1 wave
  int bad = 0;
  for (int i = lane; i < 512; i += 64) {
    float v = bf16_bits_to_f((uint32_t)xu[i]);
    if (!(v == v) || fabsf(v) > 1000.0f) bad++;
  }
  for (int off = 32; off > 0; off >>= 1) bad += __shfl_down(bad, off);
  if (lane == 0) *flag = (bad < 32) ? 1 : 0;
}

// ---------------------------------------------------------------------------
// K1: tiny precomputes.
//  WcT[t][i] (f32, t-major) = sum_r W_qkv[t][r] * W_down[r][i]
//  W_up_s[o][r] = W_up[o][r] * diag_b[o] * 4.0   (SCALING = 32/8)
//  b_pre_f[o]   = b_pre[o]
__global__ __launch_bounds__(256) void k_prep(
    const void* W_down, const void* W_qkv, const void* W_up,
    const void* diag_b, const void* b_pre,
    float* WcT, float* W_up_s, float* b_pre_f, const int* flagp) {
  const int flag = *flagp;
  const int tid = blockIdx.x * 256 + threadIdx.x;  // 192*256 = 49152 = 12*4096
  const int tt = tid >> 12;      // 0..11
  const int i = tid & 4095;
  float s = 0.f;
#pragma unroll
  for (int r = 0; r < 8; ++r)
    s += dload(W_qkv, tt * 8 + r, flag) * dload(W_down, (size_t)r * 4096 + i, flag);
  WcT[(size_t)tt * 4096 + i] = s;
  if (tid < 32768)
    W_up_s[tid] = dload(W_up, tid, flag) * dload(diag_b, tid >> 3, flag) * 4.0f;
  if (tid < 4096)
    b_pre_f[tid] = dload(b_pre, tid, flag);
}

// ---------------------------------------------------------------------------
// K2: qkv[m][t] = sum_i x[m][i]*WcT[t][i], one wave per row m, float4 loads.
// Fused: when do_conv && !flag, also writes x converted to bf16 (for k_gemm).
__global__ __launch_bounds__(256) void k_qkv(const void* x, const float* WcT,
                                             float* qkv, uint16_t* xb,
                                             int do_conv, const int* flagp) {
  const int flag = *flagp;
  const int wv = (int)((blockIdx.x * 256 + threadIdx.x) >> 6);  // row 0..8191
  const int lane = threadIdx.x & 63;
  float acc[12];
#pragma unroll
  for (int t = 0; t < 12; ++t) acc[t] = 0.f;
  if (!flag) {
    const float* xr = (const float*)x + (size_t)wv * KDIM;
    uint16_t* xo = xb + (size_t)wv * KDIM;
    for (int i0 = 0; i0 < KDIM; i0 += 256) {
      const int i = i0 + lane * 4;
      const float4 xv = *(const float4*)(xr + i);
      if (do_conv) {
        uint2 p;
        p.x = pk2(xv.x, xv.y);
        p.y = pk2(xv.z, xv.w);
        *(uint2*)(xo + i) = p;
      }
#pragma unroll
      for (int t = 0; t < 12; ++t) {
        const float4 w4 = *(const float4*)(WcT + (size_t)t * 4096 + i);
        acc[t] += xv.x * w4.x + xv.y * w4.y + xv.z * w4.z + xv.w * w4.w;
      }
    }
  } else {
    const uint16_t* xr = (const uint16_t*)x + (size_t)wv * KDIM;
    for (int i0 = 0; i0 < KDIM; i0 += 512) {
      const int i = i0 + lane * 8;
      const uint4 xv = *(const uint4*)(xr + i);
      const float x0 = bf16_bits_to_f(xv.x & 0xFFFFu), x1 = bf16_bits_to_f(xv.x >> 16);
      const float x2 = bf16_bits_to_f(xv.y & 0xFFFFu), x3 = bf16_bits_to_f(xv.y >> 16);
      const float x4 = bf16_bits_to_f(xv.z & 0xFFFFu), x5 = bf16_bits_to_f(xv.z >> 16);
      const float x6 = bf16_bits_to_f(xv.w & 0xFFFFu), x7 = bf16_bits_to_f(xv.w >> 16);
#pragma unroll
      for (int t = 0; t < 12; ++t) {
        const float4 w0 = *(const float4*)(WcT + (size_t)t * 4096 + i);
        const float4 w1 = *(const float4*)(WcT + (size_t)t * 4096 + i + 4);
        acc[t] += x0 * w0.x + x1 * w0.y + x2 * w0.z + x3 * w0.w +
                  x4 * w1.x + x5 * w1.y + x6 * w1.z + x7 * w1.w;
      }
    }
  }
#pragma unroll
  for (int t = 0; t < 12; ++t)
    for (int off = 32; off > 0; off >>= 1) acc[t] += __shfl_down(acc[t], off);
  if (lane == 0) {
#pragma unroll
    for (int t = 0; t < 12; ++t) qkv[(size_t)wv * 12 + t] = acc[t];
  }
}

// ---------------------------------------------------------------------------
// K2b: W_pre f32 -> bf16 (skipped entirely when storage is already bf16).
__global__ __launch_bounds__(256) void k_convW(const float* w, uint16_t* wb,
                                               const int* flagp) {
  if (*flagp) return;
  const size_t n = (size_t)NDIM * KDIM;
  const size_t stride = (size_t)2048 * 256 * 8;
  for (size_t idx = ((size_t)blockIdx.x * 256 + threadIdx.x) * 8; idx < n;
       idx += stride) {
    const float4 a = *(const float4*)(w + idx);
    const float4 b = *(const float4*)(w + idx + 4);
    uint4 p;
    p.x = pk2(a.x, a.y);
    p.y = pk2(a.z, a.w);
    p.z = pk2(b.x, b.y);
    p.w = pk2(b.z, b.w);
    *(uint4*)(wb + idx) = p;
  }
}

// ---------------------------------------------------------------------------
// K3: per-batch attention (head dim 4) + fold W_o. 128 blocks: each handles
// 64 q-rows; 4 K-segments per row computed by 4 threads, partials (linear in
// the no-max-subtraction softmax: l=sum e, c=sum e*v) combined via LDS.
__global__ __launch_bounds__(256) void k_attn(const float* qkv, const void* W_o,
                                              float* a_o, const int* flagp) {
  const int flag = *flagp;
  __shared__ uint2 sk[SEQ];          // k rows, 4 x bf16 packed
  __shared__ uint2 sv[SEQ];          // v rows
  __shared__ float part[4][64][9];   // seg, row, {l,c0..c3}, pad 9 vs banks
  const int b = blockIdx.x >> 5;     // batch 0..3
  const int rb = blockIdx.x & 31;    // row-block 0..31 (64 rows each)
  for (int j = threadIdx.x; j < SEQ; j += 256) {
    const float* qr = qkv + ((size_t)b * SEQ + j) * 12;
    uint2 pk, pv;
    pk.x = pk2(qr[4], qr[5]);
    pk.y = pk2(qr[6], qr[7]);
    pv.x = pk2(qr[8], qr[9]);
    pv.y = pk2(qr[10], qr[11]);
    sk[j] = pk;
    sv[j] = pv;
  }
  __syncthreads();
  const int row = threadIdx.x & 63;
  const int seg = threadIdx.x >> 6;  // 0..3, K-segment of 512
  const size_t m = (size_t)b * SEQ + rb * 64 + row;
  const float* qr = qkv + m * 12;
  const float q0 = qr[0] * 0.5f, q1 = qr[1] * 0.5f;  // 1/sqrt(4) folded
  const float q2 = qr[2] * 0.5f, q3 = qr[3] * 0.5f;
  float l = 0.f, c0 = 0.f, c1 = 0.f, c2 = 0.f, c3 = 0.f;
  const int j0 = seg * 512;
  for (int j = j0; j < j0 + 512; ++j) {
    const uint2 kk = sk[j];  // LDS broadcast within wave
    const float k0 = bf16_bits_to_f(kk.x & 0xFFFFu);
    const float k1 = bf16_bits_to_f(kk.x >> 16);
    const float k2 = bf16_bits_to_f(kk.y & 0xFFFFu);
    const float k3 = bf16_bits_to_f(kk.y >> 16);
    const float s = q0 * k0 + q1 * k1 + q2 * k2 + q3 * k3;
    const float e = __expf(s);  // |s| bounded, safe without max-subtraction
    const uint2 vv = sv[j];
    l += e;
    c0 += e * bf16_bits_to_f(vv.x & 0xFFFFu);
    c1 += e * bf16_bits_to_f(vv.x >> 16);
    c2 += e * bf16_bits_to_f(vv.y & 0xFFFFu);
    c3 += e * bf16_bits_to_f(vv.y >> 16);
  }
  part[seg][row][0] = l;
  part[seg][row][1] = c0;
  part[seg][row][2] = c1;
  part[seg][row][3] = c2;
  part[seg][row][4] = c3;
  __syncthreads();
  if (seg == 0) {
    l = part[0][row][0] + part[1][row][0] + part[2][row][0] + part[3][row][0];
    c0 = part[0][row][1] + part[1][row][1] + part[2][row][1] + part[3][row][1];
    c1 = part[0][row][2] + part[1][row][2] + part[2][row][2] + part[3][row][2];
    c2 = part[0][row][3] + part[1][row][3] + part[2][row][3] + part[3][row][3];
    c3 = part[0][row][4] + part[1][row][4] + part[2][row][4] + part[3][row][4];
    const float inv = 1.0f / l;
    c0 *= inv; c1 *= inv; c2 *= inv; c3 *= inv;
    float wo[32];
#pragma unroll
    for (int i = 0; i < 32; ++i) wo[i] = dload(W_o, i, flag);
#pragma unroll
    for (int r = 0; r < 8; ++r)
      a_o[m * 8 + r] = c0 * wo[r * 4 + 0] + c1 * wo[r * 4 + 1] +
                       c2 * wo[r * 4 + 2] + c3 * wo[r * 4 + 3];
  }
}

// ---------------------------------------------------------------------------
// K4 (fast): m97-structure GEMM. bf16 operands in global (original input if
// flag==1, workspace-converted otherwise). 128x128 tile, BK=64, 4 waves,
// global_load_lds width=16 staging, 2-barrier loop, fused adapter epilogue.
__global__ __launch_bounds__(256) void k_gemm_lds(
    const void* x, const void* w, const uint16_t* xb, const uint16_t* wb,
    const float* a_o, const float* W_up_s, const float* b_pre_f, void* out,
    const int* flagp) {
  const int flag = *flagp;
  const uint16_t* Abase = flag ? (const uint16_t*)x : xb;
  const uint16_t* Bbase = flag ? (const uint16_t*)w : wb;
  __shared__ __align__(16) uint16_t sA[128 * 64];
  __shared__ __align__(16) uint16_t sB[128 * 64];
  const int t = threadIdx.x;
  const int lane = t & 63;
  const int wid = t >> 6;
  const int bm = blockIdx.x & 63;   // 64 m-tiles
  const int bn = blockIdx.x >> 6;   // 32 n-tiles
  // staging map: wave w, call c covers LDS rows w*32+c*8 .. +8 (1 KiB/call).
  // lane l -> row w*32+c*8+(l>>3), col elems (l&7)*8 (HW adds lane*16 B).
  const int srow = wid * 32 + (lane >> 3);
  const int scol = (lane & 7) * 8;
  const uint16_t* gA = Abase + (size_t)(bm * 128 + srow) * KDIM + scol;
  const uint16_t* gB = Bbase + (size_t)(bn * 128 + srow) * KDIM + scol;
  uint16_t* lA = &sA[wid * 2048];   // + c*512 elems per call (wave-uniform)
  uint16_t* lB = &sB[wid * 2048];
  // wave/fragment map
  const int wm = (wid & 1) * 64;
  const int wn = (wid >> 1) * 64;
  const int fr = lane & 15;          // fragment row (A: m, B: n)
  const int fk = (lane >> 4) * 8;    // fragment k offset
  f32x4 acc[4][4];
#pragma unroll
  for (int a = 0; a < 4; ++a)
#pragma unroll
    for (int bq = 0; bq < 4; ++bq) acc[a][bq] = (f32x4){0.f, 0.f, 0.f, 0.f};

  for (int k0 = 0; k0 < KDIM; k0 += 64) {
    __syncthreads();  // all waves done reading previous tile
#pragma unroll
    for (int c = 0; c < 4; ++c) {
      gld_lds16(gA + (size_t)c * (8 * KDIM) + k0, lA + c * 512);
      gld_lds16(gB + (size_t)c * (8 * KDIM) + k0, lB + c * 512);
    }
    __syncthreads();  // compiler drains vmcnt(0) before s_barrier
#pragma unroll
    for (int kk = 0; kk < 64; kk += 32) {
      short8 af[4], bfr[4];
#pragma unroll
      for (int mb = 0; mb < 4; ++mb)
        af[mb] = *(const short8*)&sA[(wm + mb * 16 + fr) * 64 + kk + fk];
#pragma unroll
      for (int nb = 0; nb < 4; ++nb)
        bfr[nb] = *(const short8*)&sB[(wn + nb * 16 + fr) * 64 + kk + fk];
#pragma unroll
      for (int mb = 0; mb < 4; ++mb)
#pragma unroll
        for (int nb = 0; nb < 4; ++nb)
          acc[mb][nb] = __builtin_amdgcn_mfma_f32_16x16x32_bf16(
              af[mb], bfr[nb], acc[mb][nb], 0, 0, 0);
    }
  }
  // Epilogue. C/D map (verified m89/m91): col = lane&15, row = (lane>>4)*4+reg
  const int rq = (lane >> 4) * 4;
#pragma unroll
  for (int nb = 0; nb < 4; ++nb) {
    const int gn = bn * 128 + wn + nb * 16 + fr;
    const float bp = b_pre_f[gn];
    const float4 u0 = *(const float4*)&W_up_s[(size_t)gn * 8];
    const float4 u1 = *(const float4*)&W_up_s[(size_t)gn * 8 + 4];
#pragma unroll
    for (int mb = 0; mb < 4; ++mb) {
#pragma unroll
      for (int r = 0; r < 4; ++r) {
        const int gm = bm * 128 + wm + mb * 16 + rq + r;
        const float4 a0 = *(const float4*)&a_o[(size_t)gm * 8];
        const float4 a1 = *(const float4*)&a_o[(size_t)gm * 8 + 4];
        float v = acc[mb][nb][r] + bp + a0.x * u0.x + a0.y * u0.y +
                  a0.z * u0.z + a0.w * u0.w + a1.x * u1.x + a1.y * u1.y +
                  a1.z * u1.z + a1.w * u1.w;
        const size_t oidx = (size_t)gm * NDIM + gn;
        if (flag) ((uint16_t*)out)[oidx] = f2b(v);
        else ((float*)out)[oidx] = v;
      }
    }
  }
}

// ---------------------------------------------------------------------------
// K4 (fallback, verified previous version): used only if workspace is too
// small to hold bf16-converted operands. Reads raw x/W_pre (dual dtype).
__global__ __launch_bounds__(256) void k_gemm_fb(
    const void* x, const void* w, const float* a_o, const float* W_up_s,
    const float* b_pre_f, void* out, const int* flagp) {
  const int flag = *flagp;
  __shared__ __align__(16) uint16_t sA[128 * 64];
  __shared__ __align__(16) uint16_t sB[128 * 64];
  const int t = threadIdx.x;
  const int bm = blockIdx.x & 63;
  const int bn = blockIdx.x >> 6;
  const int srow = t >> 1;
  const int scol = (t & 1) * 32;
  const size_t ga = ((size_t)(bm * 128 + srow)) * KDIM + scol;
  const size_t gb = ((size_t)(bn * 128 + srow)) * KDIM + scol;
  const int lane = t & 63;
  const int wid = t >> 6;
  const int wm = (wid & 1) * 64;
  const int wn = (wid >> 1) * 64;
  const int fr = lane & 15;
  const int fk = (lane >> 4) * 8;
  f32x4 acc[4][4];
#pragma unroll
  for (int a = 0; a < 4; ++a)
#pragma unroll
    for (int bq = 0; bq < 4; ++bq) acc[a][bq] = (f32x4){0.f, 0.f, 0.f, 0.f};

  for (int k0 = 0; k0 < KDIM; k0 += 64) {
    __syncthreads();
    if (flag) {
      const uint16_t* gx = (const uint16_t*)x + ga + k0;
      const uint16_t* gw = (const uint16_t*)w + gb + k0;
#pragma unroll
      for (int c = 0; c < 4; ++c) {
        *(uint4*)&sA[srow * 64 + scol + c * 8] = *(const uint4*)(gx + c * 8);
        *(uint4*)&sB[srow * 64 + scol + c * 8] = *(const uint4*)(gw + c * 8);
      }
    } else {
      const float* gx = (const float*)x + ga + k0;
      const float* gw = (const float*)w + gb + k0;
#pragma unroll
      for (int c = 0; c < 4; ++c) {
        float4 xa = *(const float4*)(gx + c * 8);
        float4 xb2 = *(const float4*)(gx + c * 8 + 4);
        uint4 pk;
        pk.x = pk2(xa.x, xa.y);
        pk.y = pk2(xa.z, xa.w);
        pk.z = pk2(xb2.x, xb2.y);
        pk.w = pk2(xb2.z, xb2.w);
        *(uint4*)&sA[srow * 64 + scol + c * 8] = pk;
        float4 wa = *(const float4*)(gw + c * 8);
        float4 wb2 = *(const float4*)(gw + c * 8 + 4);
        uint4 pw;
        pw.x = pk2(wa.x, wa.y);
        pw.y = pk2(wa.z, wa.w);
        pw.z = pk2(wb2.x, wb2.y);
        pw.w = pk2(wb2.z, wb2.w);
        *(uint4*)&sB[srow * 64 + scol + c * 8] = pw;
      }
    }
    __syncthreads();
#pragma unroll
    for (int kk = 0; kk < 64; kk += 32) {
      short8 af[4], bfr[4];
#pragma unroll
      for (int mb = 0; mb < 4; ++mb)
        af[mb] = *(const short8*)&sA[(wm + mb * 16 + fr) * 64 + kk + fk];
#pragma unroll
      for (int nb = 0; nb < 4; ++nb)
        bfr[nb] = *(const short8*)&sB[(wn + nb * 16 + fr) * 64 + kk + fk];
#pragma unroll
      for (int mb = 0; mb < 4; ++mb)
#pragma unroll
        for (int nb = 0; nb < 4; ++nb)
          acc[mb][nb] = __builtin_amdgcn_mfma_f32_16x16x32_bf16(
              af[mb], bfr[nb], acc[mb][nb], 0, 0, 0);
    }
  }
  const int rq = (lane >> 4) * 4;
#pragma unroll
  for (int nb = 0; nb < 4; ++nb) {
    const int gn = bn * 128 + wn + nb * 16 + fr;
    const float bp = b_pre_f[gn];
    const float4 u0 = *(const float4*)&W_up_s[(size_t)gn * 8];
    const float4 u1 = *(const float4*)&W_up_s[(size_t)gn * 8 + 4];
#pragma unroll
    for (int mb = 0; mb < 4; ++mb) {
#pragma unroll
      for (int r = 0; r < 4; ++r) {
        const int gm = bm * 128 + wm + mb * 16 + rq + r;
        const float4 a0 = *(const float4*)&a_o[(size_t)gm * 8];
        const float4 a1 = *(const float4*)&a_o[(size_t)gm * 8 + 4];
        float v = acc[mb][nb][r] + bp + a0.x * u0.x + a0.y * u0.y +
                  a0.z * u0.z + a0.w * u0.w + a1.x * u1.x + a1.y * u1.y +
                  a1.z * u1.z + a1.w * u1.w;
        const size_t oidx = (size_t)gm * NDIM + gn;
        if (flag) ((uint16_t*)out)[oidx] = f2b(v);
        else ((float*)out)[oidx] = v;
      }
    }
  }
}

// ---------------------------------------------------------------------------
extern "C" void kernel_launch(void* const* d_in, const int* in_sizes, int n_in,
                              void* d_out, int out_size, void* d_ws,
                              size_t ws_size, hipStream_t stream) {
  const void* x = d_in[0];       // [4,2048,4096]
  const void* W_pre = d_in[1];   // [4096,4096]
  const void* b_pre = d_in[2];   // [4096]
  const void* W_down = d_in[3];  // [8,4096]
  const void* W_qkv = d_in[4];   // [12,8]
  const void* W_o = d_in[5];     // [8,4]
  const void* W_up = d_in[6];    // [4096,8]
  const void* diag_b = d_in[7];  // [4096]

  char* ws = (char*)d_ws;
  int* flag_p = (int*)ws;                        // @0
  float* WcT = (float*)(ws + 256);               // [12][4096] f32, 196608 B
  float* qkv = (float*)(ws + 196864);            // [8192][12] f32, 393216 B
  float* a_o = (float*)(ws + 590080);            // [8192][8]  f32, 262144 B
  float* W_up_s = (float*)(ws + 852224);         // [4096][8]  f32, 131072 B
  float* b_pre_f = (float*)(ws + 983296);        // [4096]     f32, 16384 B
  uint16_t* xb = (uint16_t*)(ws + 1048576);      // [8192][4096] bf16, 64 MiB
  uint16_t* wb = (uint16_t*)(ws + 68157440);     // [4096][4096] bf16, 32 MiB
  const bool big = ws_size >= (size_t)101711872; // room for xb+wb?

  k_detect<<<1, 64, 0, stream>>>((const uint16_t*)x, flag_p);
  k_prep<<<192, 256, 0, stream>>>(W_down, W_qkv, W_up, diag_b, b_pre, WcT,
                                  W_up_s, b_pre_f, flag_p);
  k_qkv<<<2048, 256, 0, stream>>>(x, WcT, qkv, xb, big ? 1 : 0, flag_p);
  if (big)
    k_convW<<<2048, 256, 0, stream>>>((const float*)W_pre, wb, flag_p);
  k_attn<<<128, 256, 0, stream>>>(qkv, W_o, a_o, flag_p);
  if (big)
    k_gemm_lds<<<2048, 256, 0, stream>>>(x, W_pre, xb, wb, a_o, W_up_s,
                                         b_pre_f, d_out, flag_p);
  else
    k_gemm_fb<<<2048, 256, 0, stream>>>(x, W_pre, a_o, W_up_s, b_pre_f, d_out,
                                        flag_p);
}

// Round 2
// 613.621 us; speedup vs baseline: 2.6642x; 1.3139x over previous
//
#include <hip/hip_runtime.h>
#include <stdint.h>

// Problem constants
#define KDIM 4096   // IN_DIM
#define NDIM 4096   // OUT_DIM
#define MROWS 8192  // 4*2048
#define SEQ 2048

typedef __attribute__((ext_vector_type(8))) short short8;
typedef __attribute__((ext_vector_type(4))) float f32x4;

__device__ __forceinline__ float bf16_bits_to_f(uint32_t u16) {
  union { uint32_t u; float f; } c; c.u = u16 << 16; return c.f;
}
__device__ __forceinline__ float dload(const void* p, size_t idx, int flag) {
  if (flag) return bf16_bits_to_f(((const uint16_t*)p)[idx]);
  return ((const float*)p)[idx];
}
__device__ __forceinline__ uint16_t f2b(float f) {  // RNE f32->bf16
  union { float f; uint32_t u; } c; c.f = f;
  uint32_t b = c.u;
  return (uint16_t)((b + 0x7FFFu + ((b >> 16) & 1u)) >> 16);
}
__device__ __forceinline__ uint32_t pk2(float a, float b) {
  return (uint32_t)f2b(a) | ((uint32_t)f2b(b) << 16);
}
// async global->LDS, 16B per lane. LDS dest = wave-uniform base + lane*16.
__device__ __forceinline__ void gld_lds16(const uint16_t* g, uint16_t* l) {
  __builtin_amdgcn_global_load_lds(
      (const __attribute__((address_space(1))) uint32_t*)g,
      (__attribute__((address_space(3))) uint32_t*)l, 16, 0, 0);
}

#define BARRIER() asm volatile("s_barrier" ::: "memory")
#define VMCNT4() asm volatile("s_waitcnt vmcnt(4)" ::: "memory")
#define VMCNT0() asm volatile("s_waitcnt vmcnt(0)" ::: "memory")

// ---------------------------------------------------------------------------
// K0: dtype detection (verified). flag=1 means bf16 storage.
__global__ void k_detect(const uint16_t* xu, int* flag) {
  int lane = threadIdx.x;
  int bad = 0;
  for (int i = lane; i < 512; i += 64) {
    float v = bf16_bits_to_f((uint32_t)xu[i]);
    if (!(v == v) || fabsf(v) > 1000.0f) bad++;
  }
  for (int off = 32; off > 0; off >>= 1) bad += __shfl_down(bad, off);
  if (lane == 0) *flag = (bad < 32) ? 1 : 0;
}

// ---------------------------------------------------------------------------
// K1: tiny precomputes (verified round 1).
__global__ __launch_bounds__(256) void k_prep(
    const void* W_down, const void* W_qkv, const void* W_up,
    const void* diag_b, const void* b_pre,
    float* WcT, float* W_up_s, float* b_pre_f, const int* flagp) {
  const int flag = *flagp;
  const int tid = blockIdx.x * 256 + threadIdx.x;
  const int tt = tid >> 12;
  const int i = tid & 4095;
  float s = 0.f;
#pragma unroll
  for (int r = 0; r < 8; ++r)
    s += dload(W_qkv, tt * 8 + r, flag) * dload(W_down, (size_t)r * 4096 + i, flag);
  WcT[(size_t)tt * 4096 + i] = s;
  if (tid < 32768)
    W_up_s[tid] = dload(W_up, tid, flag) * dload(diag_b, tid >> 3, flag) * 4.0f;
  if (tid < 4096)
    b_pre_f[tid] = dload(b_pre, tid, flag);
}

// ---------------------------------------------------------------------------
// K2: fused qkv + x->bf16 conversion (blocks < 2048) and W_pre->bf16
// conversion (blocks 2048..2559). Both memory-bound, run concurrently.
__global__ __launch_bounds__(256) void k_qkvconv(
    const void* x, const float* WcT, float* qkv, uint16_t* xb,
    const void* W_pre, uint16_t* wb, int do_conv, const int* flagp) {
  const int flag = *flagp;
  if (blockIdx.x >= 2048) {
    // W_pre conversion part (512 blocks)
    if (flag || !do_conv) return;
    const float* w = (const float*)W_pre;
    const size_t n = (size_t)NDIM * KDIM;
    const size_t stride = (size_t)512 * 256 * 8;
    for (size_t idx = (((size_t)blockIdx.x - 2048) * 256 + threadIdx.x) * 8;
         idx < n; idx += stride) {
      const float4 a = *(const float4*)(w + idx);
      const float4 b = *(const float4*)(w + idx + 4);
      uint4 p;
      p.x = pk2(a.x, a.y);
      p.y = pk2(a.z, a.w);
      p.z = pk2(b.x, b.y);
      p.w = pk2(b.z, b.w);
      *(uint4*)(wb + idx) = p;
    }
    return;
  }
  const int wv = (int)((blockIdx.x * 256 + threadIdx.x) >> 6);  // row 0..8191
  const int lane = threadIdx.x & 63;
  float acc[12];
#pragma unroll
  for (int t = 0; t < 12; ++t) acc[t] = 0.f;
  if (!flag) {
    const float* xr = (const float*)x + (size_t)wv * KDIM;
    uint16_t* xo = xb + (size_t)wv * KDIM;
    for (int i0 = 0; i0 < KDIM; i0 += 256) {
      const int i = i0 + lane * 4;
      const float4 xv = *(const float4*)(xr + i);
      if (do_conv) {
        uint2 p;
        p.x = pk2(xv.x, xv.y);
        p.y = pk2(xv.z, xv.w);
        *(uint2*)(xo + i) = p;
      }
#pragma unroll
      for (int t = 0; t < 12; ++t) {
        const float4 w4 = *(const float4*)(WcT + (size_t)t * 4096 + i);
        acc[t] += xv.x * w4.x + xv.y * w4.y + xv.z * w4.z + xv.w * w4.w;
      }
    }
  } else {
    const uint16_t* xr = (const uint16_t*)x + (size_t)wv * KDIM;
    for (int i0 = 0; i0 < KDIM; i0 += 512) {
      const int i = i0 + lane * 8;
      const uint4 xv = *(const uint4*)(xr + i);
      const float x0 = bf16_bits_to_f(xv.x & 0xFFFFu), x1 = bf16_bits_to_f(xv.x >> 16);
      const float x2 = bf16_bits_to_f(xv.y & 0xFFFFu), x3 = bf16_bits_to_f(xv.y >> 16);
      const float x4 = bf16_bits_to_f(xv.z & 0xFFFFu), x5 = bf16_bits_to_f(xv.z >> 16);
      const float x6 = bf16_bits_to_f(xv.w & 0xFFFFu), x7 = bf16_bits_to_f(xv.w >> 16);
#pragma unroll
      for (int t = 0; t < 12; ++t) {
        const float4 w0 = *(const float4*)(WcT + (size_t)t * 4096 + i);
        const float4 w1 = *(const float4*)(WcT + (size_t)t * 4096 + i + 4);
        acc[t] += x0 * w0.x + x1 * w0.y + x2 * w0.z + x3 * w0.w +
                  x4 * w1.x + x5 * w1.y + x6 * w1.z + x7 * w1.w;
      }
    }
  }
#pragma unroll
  for (int t = 0; t < 12; ++t)
    for (int off = 32; off > 0; off >>= 1) acc[t] += __shfl_down(acc[t], off);
  if (lane == 0) {
#pragma unroll
    for (int t = 0; t < 12; ++t) qkv[(size_t)wv * 12 + t] = acc[t];
  }
}

// ---------------------------------------------------------------------------
// K3: per-batch attention (verified round 1).
__global__ __launch_bounds__(256) void k_attn(const float* qkv, const void* W_o,
                                              float* a_o, const int* flagp) {
  const int flag = *flagp;
  __shared__ uint2 sk[SEQ];
  __shared__ uint2 sv[SEQ];
  __shared__ float part[4][64][9];
  const int b = blockIdx.x >> 5;
  const int rb = blockIdx.x & 31;
  for (int j = threadIdx.x; j < SEQ; j += 256) {
    const float* qr = qkv + ((size_t)b * SEQ + j) * 12;
    uint2 pk, pv;
    pk.x = pk2(qr[4], qr[5]);
    pk.y = pk2(qr[6], qr[7]);
    pv.x = pk2(qr[8], qr[9]);
    pv.y = pk2(qr[10], qr[11]);
    sk[j] = pk;
    sv[j] = pv;
  }
  __syncthreads();
  const int row = threadIdx.x & 63;
  const int seg = threadIdx.x >> 6;
  const size_t m = (size_t)b * SEQ + rb * 64 + row;
  const float* qr = qkv + m * 12;
  const float q0 = qr[0] * 0.5f, q1 = qr[1] * 0.5f;
  const float q2 = qr[2] * 0.5f, q3 = qr[3] * 0.5f;
  float l = 0.f, c0 = 0.f, c1 = 0.f, c2 = 0.f, c3 = 0.f;
  const int j0 = seg * 512;
  for (int j = j0; j < j0 + 512; ++j) {
    const uint2 kk = sk[j];
    const float k0 = bf16_bits_to_f(kk.x & 0xFFFFu);
    const float k1 = bf16_bits_to_f(kk.x >> 16);
    const float k2 = bf16_bits_to_f(kk.y & 0xFFFFu);
    const float k3 = bf16_bits_to_f(kk.y >> 16);
    const float s = q0 * k0 + q1 * k1 + q2 * k2 + q3 * k3;
    const float e = __expf(s);
    const uint2 vv = sv[j];
    l += e;
    c0 += e * bf16_bits_to_f(vv.x & 0xFFFFu);
    c1 += e * bf16_bits_to_f(vv.x >> 16);
    c2 += e * bf16_bits_to_f(vv.y & 0xFFFFu);
    c3 += e * bf16_bits_to_f(vv.y >> 16);
  }
  part[seg][row][0] = l;
  part[seg][row][1] = c0;
  part[seg][row][2] = c1;
  part[seg][row][3] = c2;
  part[seg][row][4] = c3;
  __syncthreads();
  if (seg == 0) {
    l = part[0][row][0] + part[1][row][0] + part[2][row][0] + part[3][row][0];
    c0 = part[0][row][1] + part[1][row][1] + part[2][row][1] + part[3][row][1];
    c1 = part[0][row][2] + part[1][row][2] + part[2][row][2] + part[3][row][2];
    c2 = part[0][row][3] + part[1][row][3] + part[2][row][3] + part[3][row][3];
    c3 = part[0][row][4] + part[1][row][4] + part[2][row][4] + part[3][row][4];
    const float inv = 1.0f / l;
    c0 *= inv; c1 *= inv; c2 *= inv; c3 *= inv;
    float wo[32];
#pragma unroll
    for (int i = 0; i < 32; ++i) wo[i] = dload(W_o, i, flag);
#pragma unroll
    for (int r = 0; r < 8; ++r)
      a_o[m * 8 + r] = c0 * wo[r * 4 + 0] + c1 * wo[r * 4 + 1] +
                       c2 * wo[r * 4 + 2] + c3 * wo[r * 4 + 3];
  }
}

// ---------------------------------------------------------------------------
// K4: 256x256 8-phase GEMM (T2 st_16x32 swizzle + T3/T4 counted vmcnt + T5).
// C[m][n] = sum_k A[m][k]*B[n][k] + fused adapter epilogue.
// 512 thr = 8 waves (2Mx4N); per-wave output 128x64; BK=64; LDS 128 KiB.
// Schedule (per iter, tiles tE=2it -> buf0, tO=2it+1 -> buf1):
//  ph0: ldA(b0,m0)+ldB(b0,n0); stage b1.A0(tO)   | MFMA q(0,0)
//  ph1: ldB(b0,n1);            stage b1.A1(tO)   | MFMA q(0,1)
//  ph2: ldA(b0,m1);            stage b0.B0(tE+2) | MFMA q(1,0)
//  ph3:                        stage b0.B1(tE+2) | MFMA q(1,1); vmcnt(4)
//  ph4: ldA(b1,m0)+ldB(b1,n0); stage b0.A0(tE+2) | MFMA q(0,0)
//  ph5: ldB(b1,n1);            stage b0.A1(tE+2) | MFMA q(0,1)
//  ph6: ldA(b1,m1);            stage b1.B0(tE+3) | MFMA q(1,0)
//  ph7:                        stage b1.B1(tE+3) | MFMA q(1,1); vmcnt(4)
// Region legality: buf.B free after ph1/ph5-end; buf.A free after ph2/ph6-end.
// vmcnt(4) leaves exactly 2 half-tiles (4 loads) in flight; never drains to 0.
__global__ __launch_bounds__(512, 2) void k_gemm8(
    const void* x, const void* w, const uint16_t* xb, const uint16_t* wb,
    const float* a_o, const float* W_up_s, const float* b_pre_f, void* out,
    const int* flagp) {
  const int flag = *flagp;
  const uint16_t* Ag = flag ? (const uint16_t*)x : xb;
  const uint16_t* Bg = flag ? (const uint16_t*)w : wb;
  __shared__ __align__(16) uint16_t smem[2][2][16384];  // [buf][A/B][256*64]

  const int t = threadIdx.x;
  const int lane = t & 63;
  const int wid = t >> 6;
  // bijective XCD swizzle (512 % 8 == 0): each XCD gets 64 consecutive wgs
  const int swz = ((int)blockIdx.x & 7) * 64 + ((int)blockIdx.x >> 3);
  const int bm = swz & 31;   // 32 m-tiles (M=8192)
  const int bn = swz >> 5;   // 16 n-tiles (N=4096)

  // staging map: call c, wave wid, lane -> row c*64+wid*8+(lane>>3),
  // col elems (lane&7)*8, XOR-swizzled by row bit2 (st_16x32: bit9->bit5)
  const int sr0 = 0 * 64 + wid * 8 + (lane >> 3);
  const int sr1 = 1 * 64 + wid * 8 + (lane >> 3);
  const int sc0 = ((lane & 7) * 8) ^ (((sr0 >> 2) & 1) * 16);
  const int sc1 = ((lane & 7) * 8) ^ (((sr1 >> 2) & 1) * 16);
  const size_t aoff0 = (size_t)(bm * 256 + sr0) * KDIM + sc0;
  const size_t aoff1 = (size_t)(bm * 256 + sr1) * KDIM + sc1;
  const size_t boff0 = (size_t)(bn * 256 + sr0) * KDIM + sc0;
  const size_t boff1 = (size_t)(bn * 256 + sr1) * KDIM + sc1;

  // wave/fragment map
  const int wn_idx = wid & 3;
  const int wm_idx = wid >> 2;
  const int wave_m0 = wm_idx * 128;  // rows within 256-tile
  const int wave_n0 = wn_idx * 64;   // cols within 256-tile
  const int fr = lane & 15;
  // swizzled k-offset (elements): fk ^ (rowbit2 * 16); rowbit2 = (fr>>2)&1
  const int fkbe = ((lane >> 4) * 8) ^ ((((lane & 15) >> 2) & 1) * 16);

  f32x4 acc[8][4];
#pragma unroll
  for (int a = 0; a < 8; ++a)
#pragma unroll
    for (int b = 0; b < 4; ++b) acc[a][b] = (f32x4){0.f, 0.f, 0.f, 0.f};

  short8 a_reg[4][2];     // current m-half: 4 m-frags x 2 k-halves
  short8 b_reg[2][2][2];  // all B: [n-half][n-frag][k-half]

#define STAGE(BUF, OP, H, TILE)                                               \
  do {                                                                        \
    const uint16_t* g_ = (OP) ? Bg : Ag;                                      \
    const size_t ho_ = (size_t)(H) * (128 * KDIM) + (size_t)(TILE) * 64;      \
    gld_lds16(g_ + ((OP) ? boff0 : aoff0) + ho_,                              \
              &smem[BUF][OP][(H) * 8192 + wid * 512]);                        \
    gld_lds16(g_ + ((OP) ? boff1 : aoff1) + ho_,                              \
              &smem[BUF][OP][(H) * 8192 + 4096 + wid * 512]);                 \
  } while (0)

#define A_LOAD(BUF, MH)                                                       \
  do {                                                                        \
    _Pragma("unroll") for (int f = 0; f < 4; ++f) {                           \
      a_reg[f][0] = *(const short8*)&smem[BUF][0][                            \
          (wave_m0 + ((MH)*4 + f) * 16 + fr) * 64 + fkbe];                    \
      a_reg[f][1] = *(const short8*)&smem[BUF][0][                            \
          (wave_m0 + ((MH)*4 + f) * 16 + fr) * 64 + 32 + fkbe];               \
    }                                                                         \
  } while (0)

#define B_LOAD(BUF, NH)                                                       \
  do {                                                                        \
    _Pragma("unroll") for (int g = 0; g < 2; ++g) {                           \
      b_reg[NH][g][0] = *(const short8*)&smem[BUF][1][                        \
          (wave_n0 + ((NH)*2 + g) * 16 + fr) * 64 + fkbe];                    \
      b_reg[NH][g][1] = *(const short8*)&smem[BUF][1][                        \
          (wave_n0 + ((NH)*2 + g) * 16 + fr) * 64 + 32 + fkbe];               \
    }                                                                         \
  } while (0)

#define MFMA_Q(MH, NH)                                                        \
  do {                                                                        \
    __builtin_amdgcn_s_setprio(1);                                            \
    _Pragma("unroll") for (int f = 0; f < 4; ++f) {                           \
      _Pragma("unroll") for (int g = 0; g < 2; ++g) {                         \
        acc[(MH)*4 + f][(NH)*2 + g] = __builtin_amdgcn_mfma_f32_16x16x32_bf16(\
            a_reg[f][0], b_reg[NH][g][0], acc[(MH)*4 + f][(NH)*2 + g], 0,0,0);\
        acc[(MH)*4 + f][(NH)*2 + g] = __builtin_amdgcn_mfma_f32_16x16x32_bf16(\
            a_reg[f][1], b_reg[NH][g][1], acc[(MH)*4 + f][(NH)*2 + g], 0,0,0);\
      }                                                                       \
    }                                                                         \
    __builtin_amdgcn_s_setprio(0);                                            \
  } while (0)

  // Prologue: t0 full (buf0) + t1.B0,B1 (buf1) = 12 loads; wait t0 landed.
  STAGE(0, 0, 0, 0); STAGE(0, 0, 1, 0); STAGE(0, 1, 0, 0); STAGE(0, 1, 1, 0);
  STAGE(1, 1, 0, 1); STAGE(1, 1, 1, 1);
  VMCNT4();
  BARRIER();

#pragma unroll 1
  for (int it = 0; it < 31; ++it) {
    const int tO = 2 * it + 1, tE2 = 2 * it + 2, tO2 = 2 * it + 3;
    // ph0
    A_LOAD(0, 0); B_LOAD(0, 0); STAGE(1, 0, 0, tO);
    BARRIER(); MFMA_Q(0, 0); BARRIER();
    // ph1
    B_LOAD(0, 1); STAGE(1, 0, 1, tO);
    BARRIER(); MFMA_Q(0, 1); BARRIER();
    // ph2
    A_LOAD(0, 1); STAGE(0, 1, 0, tE2);
    BARRIER(); MFMA_Q(1, 0); BARRIER();
    // ph3
    STAGE(0, 1, 1, tE2);
    BARRIER(); MFMA_Q(1, 1); VMCNT4(); BARRIER();
    // ph4
    A_LOAD(1, 0); B_LOAD(1, 0); STAGE(0, 0, 0, tE2);
    BARRIER(); MFMA_Q(0, 0); BARRIER();
    // ph5
    B_LOAD(1, 1); STAGE(0, 0, 1, tE2);
    BARRIER(); MFMA_Q(0, 1); BARRIER();
    // ph6
    A_LOAD(1, 1); STAGE(1, 1, 0, tO2);
    BARRIER(); MFMA_Q(1, 0); BARRIER();
    // ph7
    STAGE(1, 1, 1, tO2);
    BARRIER(); MFMA_Q(1, 1); VMCNT4(); BARRIER();
  }
  // Tail: tiles 62 (buf0), 63 (buf1). Stage only 63.A0/A1; drain at ph3.
  A_LOAD(0, 0); B_LOAD(0, 0); STAGE(1, 0, 0, 63);
  BARRIER(); MFMA_Q(0, 0); BARRIER();
  B_LOAD(0, 1); STAGE(1, 0, 1, 63);
  BARRIER(); MFMA_Q(0, 1); BARRIER();
  A_LOAD(0, 1);
  BARRIER(); MFMA_Q(1, 0); BARRIER();
  BARRIER(); MFMA_Q(1, 1); VMCNT0(); BARRIER();
  A_LOAD(1, 0); B_LOAD(1, 0);
  BARRIER(); MFMA_Q(0, 0); BARRIER();
  B_LOAD(1, 1);
  BARRIER(); MFMA_Q(0, 1); BARRIER();
  A_LOAD(1, 1);
  BARRIER(); MFMA_Q(1, 0); BARRIER();
  BARRIER(); MFMA_Q(1, 1); BARRIER();

  // Epilogue. C/D map (verified): col = lane&15, row = (lane>>4)*4 + reg.
  const int rq = (lane >> 4) * 4;
  float4 u0r[4], u1r[4];
  float bpr[4];
#pragma unroll
  for (int nf = 0; nf < 4; ++nf) {
    const int gn = bn * 256 + wave_n0 + nf * 16 + fr;
    bpr[nf] = b_pre_f[gn];
    u0r[nf] = *(const float4*)&W_up_s[(size_t)gn * 8];
    u1r[nf] = *(const float4*)&W_up_s[(size_t)gn * 8 + 4];
  }
#pragma unroll
  for (int mf = 0; mf < 8; ++mf) {
#pragma unroll
    for (int r = 0; r < 4; ++r) {
      const int gm = bm * 256 + wave_m0 + mf * 16 + rq + r;
      const float4 a0 = *(const float4*)&a_o[(size_t)gm * 8];
      const float4 a1 = *(const float4*)&a_o[(size_t)gm * 8 + 4];
#pragma unroll
      for (int nf = 0; nf < 4; ++nf) {
        const int gn = bn * 256 + wave_n0 + nf * 16 + fr;
        float v = acc[mf][nf][r] + bpr[nf] +
                  a0.x * u0r[nf].x + a0.y * u0r[nf].y + a0.z * u0r[nf].z +
                  a0.w * u0r[nf].w + a1.x * u1r[nf].x + a1.y * u1r[nf].y +
                  a1.z * u1r[nf].z + a1.w * u1r[nf].w;
        const size_t oidx = (size_t)gm * NDIM + gn;
        if (flag) ((uint16_t*)out)[oidx] = f2b(v);
        else ((float*)out)[oidx] = v;
      }
    }
  }
#undef STAGE
#undef A_LOAD
#undef B_LOAD
#undef MFMA_Q
}

// ---------------------------------------------------------------------------
// K4 fallback (verified round 0): only if workspace too small for bf16 copies.
__global__ __launch_bounds__(256) void k_gemm_fb(
    const void* x, const void* w, const float* a_o, const float* W_up_s,
    const float* b_pre_f, void* out, const int* flagp) {
  const int flag = *flagp;
  __shared__ __align__(16) uint16_t sA[128 * 64];
  __shared__ __align__(16) uint16_t sB[128 * 64];
  const int t = threadIdx.x;
  const int bm = blockIdx.x & 63;
  const int bn = blockIdx.x >> 6;
  const int srow = t >> 1;
  const int scol = (t & 1) * 32;
  const size_t ga = ((size_t)(bm * 128 + srow)) * KDIM + scol;
  const size_t gb = ((size_t)(bn * 128 + srow)) * KDIM + scol;
  const int lane = t & 63;
  const int wid = t >> 6;
  const int wm = (wid & 1) * 64;
  const int wn = (wid >> 1) * 64;
  const int fr = lane & 15;
  const int fk = (lane >> 4) * 8;
  f32x4 acc[4][4];
#pragma unroll
  for (int a = 0; a < 4; ++a)
#pragma unroll
    for (int bq = 0; bq < 4; ++bq) acc[a][bq] = (f32x4){0.f, 0.f, 0.f, 0.f};

  for (int k0 = 0; k0 < KDIM; k0 += 64) {
    __syncthreads();
    if (flag) {
      const uint16_t* gx = (const uint16_t*)x + ga + k0;
      const uint16_t* gw = (const uint16_t*)w + gb + k0;
#pragma unroll
      for (int c = 0; c < 4; ++c) {
        *(uint4*)&sA[srow * 64 + scol + c * 8] = *(const uint4*)(gx + c * 8);
        *(uint4*)&sB[srow * 64 + scol + c * 8] = *(const uint4*)(gw + c * 8);
      }
    } else {
      const float* gx = (const float*)x + ga + k0;
      const float* gw = (const float*)w + gb + k0;
#pragma unroll
      for (int c = 0; c < 4; ++c) {
        float4 xa = *(const float4*)(gx + c * 8);
        float4 xb2 = *(const float4*)(gx + c * 8 + 4);
        uint4 pk;
        pk.x = pk2(xa.x, xa.y);
        pk.y = pk2(xa.z, xa.w);
        pk.z = pk2(xb2.x, xb2.y);
        pk.w = pk2(xb2.z, xb2.w);
        *(uint4*)&sA[srow * 64 + scol + c * 8] = pk;
        float4 wa = *(const float4*)(gw + c * 8);
        float4 wb2 = *(const float4*)(gw + c * 8 + 4);
        uint4 pw;
        pw.x = pk2(wa.x, wa.y);
        pw.y = pk2(wa.z, wa.w);
        pw.z = pk2(wb2.x, wb2.y);
        pw.w = pk2(wb2.z, wb2.w);
        *(uint4*)&sB[srow * 64 + scol + c * 8] = pw;
      }
    }
    __syncthreads();
#pragma unroll
    for (int kk = 0; kk < 64; kk += 32) {
      short8 af[4], bfr[4];
#pragma unroll
      for (int mb = 0; mb < 4; ++mb)
        af[mb] = *(const short8*)&sA[(wm + mb * 16 + fr) * 64 + kk + fk];
#pragma unroll
      for (int nb = 0; nb < 4; ++nb)
        bfr[nb] = *(const short8*)&sB[(wn + nb * 16 + fr) * 64 + kk + fk];
#pragma unroll
      for (int mb = 0; mb < 4; ++mb)
#pragma unroll
        for (int nb = 0; nb < 4; ++nb)
          acc[mb][nb] = __builtin_amdgcn_mfma_f32_16x16x32_bf16(
              af[mb], bfr[nb], acc[mb][nb], 0, 0, 0);
    }
  }
  const int rq = (lane >> 4) * 4;
#pragma unroll
  for (int nb = 0; nb < 4; ++nb) {
    const int gn = bn * 128 + wn + nb * 16 + fr;
    const float bp = b_pre_f[gn];
    const float4 u0 = *(const float4*)&W_up_s[(size_t)gn * 8];
    const float4 u1 = *(const float4*)&W_up_s[(size_t)gn * 8 + 4];
#pragma unroll
    for (int mb = 0; mb < 4; ++mb) {
#pragma unroll
      for (int r = 0; r < 4; ++r) {
        const int gm = bm * 128 + wm + mb * 16 + rq + r;
        const float4 a0 = *(const float4*)&a_o[(size_t)gm * 8];
        const float4 a1 = *(const float4*)&a_o[(size_t)gm * 8 + 4];
        float v = acc[mb][nb][r] + bp + a0.x * u0.x + a0.y * u0.y +
                  a0.z * u0.z + a0.w * u0.w + a1.x * u1.x + a1.y * u1.y +
                  a1.z * u1.z + a1.w * u1.w;
        const size_t oidx = (size_t)gm * NDIM + gn;
        if (flag) ((uint16_t*)out)[oidx] = f2b(v);
        else ((float*)out)[oidx] = v;
      }
    }
  }
}

// ---------------------------------------------------------------------------
extern "C" void kernel_launch(void* const* d_in, const int* in_sizes, int n_in,
                              void* d_out, int out_size, void* d_ws,
                              size_t ws_size, hipStream_t stream) {
  const void* x = d_in[0];
  const void* W_pre = d_in[1];
  const void* b_pre = d_in[2];
  const void* W_down = d_in[3];
  const void* W_qkv = d_in[4];
  const void* W_o = d_in[5];
  const void* W_up = d_in[6];
  const void* diag_b = d_in[7];

  char* ws = (char*)d_ws;
  int* flag_p = (int*)ws;                        // @0
  float* WcT = (float*)(ws + 256);               // [12][4096] f32
  float* qkv = (float*)(ws + 196864);            // [8192][12] f32
  float* a_o = (float*)(ws + 590080);            // [8192][8]  f32
  float* W_up_s = (float*)(ws + 852224);         // [4096][8]  f32
  float* b_pre_f = (float*)(ws + 983296);        // [4096]     f32
  uint16_t* xb = (uint16_t*)(ws + 1048576);      // [8192][4096] bf16, 64 MiB
  uint16_t* wb = (uint16_t*)(ws + 68157440);     // [4096][4096] bf16, 32 MiB
  const bool big = ws_size >= (size_t)101711872;

  k_detect<<<1, 64, 0, stream>>>((const uint16_t*)x, flag_p);
  k_prep<<<192, 256, 0, stream>>>(W_down, W_qkv, W_up, diag_b, b_pre, WcT,
                                  W_up_s, b_pre_f, flag_p);
  k_qkvconv<<<2560, 256, 0, stream>>>(x, WcT, qkv, xb, W_pre, wb,
                                      big ? 1 : 0, flag_p);
  k_attn<<<128, 256, 0, stream>>>(qkv, W_o, a_o, flag_p);
  if (big)
    k_gemm8<<<512, 512, 0, stream>>>(x, W_pre, xb, wb, a_o, W_up_s, b_pre_f,
                                     d_out, flag_p);
  else
    k_gemm_fb<<<2048, 256, 0, stream>>>(x, W_pre, a_o, W_up_s, b_pre_f, d_out,
                                        flag_p);
}

// Round 3
// 597.911 us; speedup vs baseline: 2.7342x; 1.0263x over previous
//
#include <hip/hip_runtime.h>
#include <stdint.h>

// Problem constants
#define KDIM 4096   // IN_DIM
#define NDIM 4096   // OUT_DIM
#define MROWS 8192  // 4*2048
#define SEQ 2048

typedef __attribute__((ext_vector_type(8))) short short8;
typedef __attribute__((ext_vector_type(4))) float f32x4;

__device__ __forceinline__ float bf16_bits_to_f(uint32_t u16) {
  union { uint32_t u; float f; } c; c.u = u16 << 16; return c.f;
}
__device__ __forceinline__ float dload(const void* p, size_t idx, int flag) {
  if (flag) return bf16_bits_to_f(((const uint16_t*)p)[idx]);
  return ((const float*)p)[idx];
}
__device__ __forceinline__ uint16_t f2b(float f) {  // RNE f32->bf16
  union { float f; uint32_t u; } c; c.f = f;
  uint32_t b = c.u;
  return (uint16_t)((b + 0x7FFFu + ((b >> 16) & 1u)) >> 16);
}
__device__ __forceinline__ uint32_t pk2(float a, float b) {
  return (uint32_t)f2b(a) | ((uint32_t)f2b(b) << 16);
}
// async global->LDS, 16B per lane. LDS dest = wave-uniform base + lane*16.
__device__ __forceinline__ void gld_lds16(const uint16_t* g, uint16_t* l) {
  __builtin_amdgcn_global_load_lds(
      (const __attribute__((address_space(1))) uint32_t*)g,
      (__attribute__((address_space(3))) uint32_t*)l, 16, 0, 0);
}

#define BARRIER() asm volatile("s_barrier" ::: "memory")
#define VMCNT4() asm volatile("s_waitcnt vmcnt(4)" ::: "memory")
#define VMCNT0() asm volatile("s_waitcnt vmcnt(0)" ::: "memory")

// ---------------------------------------------------------------------------
// K0: dtype detection (verified). flag=1 means bf16 storage.
__global__ void k_detect(const uint16_t* xu, int* flag) {
  int lane = threadIdx.x;
  int bad = 0;
  for (int i = lane; i < 512; i += 64) {
    float v = bf16_bits_to_f((uint32_t)xu[i]);
    if (!(v == v) || fabsf(v) > 1000.0f) bad++;
  }
  for (int off = 32; off > 0; off >>= 1) bad += __shfl_down(bad, off);
  if (lane == 0) *flag = (bad < 32) ? 1 : 0;
}

// ---------------------------------------------------------------------------
// K1: tiny precomputes (verified).
__global__ __launch_bounds__(256) void k_prep(
    const void* W_down, const void* W_qkv, const void* W_up,
    const void* diag_b, const void* b_pre,
    float* WcT, float* W_up_s, float* b_pre_f, const int* flagp) {
  const int flag = *flagp;
  const int tid = blockIdx.x * 256 + threadIdx.x;
  const int tt = tid >> 12;
  const int i = tid & 4095;
  float s = 0.f;
#pragma unroll
  for (int r = 0; r < 8; ++r)
    s += dload(W_qkv, tt * 8 + r, flag) * dload(W_down, (size_t)r * 4096 + i, flag);
  WcT[(size_t)tt * 4096 + i] = s;
  if (tid < 32768)
    W_up_s[tid] = dload(W_up, tid, flag) * dload(diag_b, tid >> 3, flag) * 4.0f;
  if (tid < 4096)
    b_pre_f[tid] = dload(b_pre, tid, flag);
}

// ---------------------------------------------------------------------------
// K2: fused qkv + x->bf16 conversion (blocks < 2048) and W_pre->bf16
// conversion (blocks 2048..2559). Both memory-bound, run concurrently.
__global__ __launch_bounds__(256) void k_qkvconv(
    const void* x, const float* WcT, float* qkv, uint16_t* xb,
    const void* W_pre, uint16_t* wb, int do_conv, const int* flagp) {
  const int flag = *flagp;
  if (blockIdx.x >= 2048) {
    if (flag || !do_conv) return;
    const float* w = (const float*)W_pre;
    const size_t n = (size_t)NDIM * KDIM;
    const size_t stride = (size_t)512 * 256 * 8;
    for (size_t idx = (((size_t)blockIdx.x - 2048) * 256 + threadIdx.x) * 8;
         idx < n; idx += stride) {
      const float4 a = *(const float4*)(w + idx);
      const float4 b = *(const float4*)(w + idx + 4);
      uint4 p;
      p.x = pk2(a.x, a.y);
      p.y = pk2(a.z, a.w);
      p.z = pk2(b.x, b.y);
      p.w = pk2(b.z, b.w);
      *(uint4*)(wb + idx) = p;
    }
    return;
  }
  const int wv = (int)((blockIdx.x * 256 + threadIdx.x) >> 6);  // row 0..8191
  const int lane = threadIdx.x & 63;
  float acc[12];
#pragma unroll
  for (int t = 0; t < 12; ++t) acc[t] = 0.f;
  if (!flag) {
    const float* xr = (const float*)x + (size_t)wv * KDIM;
    uint16_t* xo = xb + (size_t)wv * KDIM;
    for (int i0 = 0; i0 < KDIM; i0 += 256) {
      const int i = i0 + lane * 4;
      const float4 xv = *(const float4*)(xr + i);
      if (do_conv) {
        uint2 p;
        p.x = pk2(xv.x, xv.y);
        p.y = pk2(xv.z, xv.w);
        *(uint2*)(xo + i) = p;
      }
#pragma unroll
      for (int t = 0; t < 12; ++t) {
        const float4 w4 = *(const float4*)(WcT + (size_t)t * 4096 + i);
        acc[t] += xv.x * w4.x + xv.y * w4.y + xv.z * w4.z + xv.w * w4.w;
      }
    }
  } else {
    const uint16_t* xr = (const uint16_t*)x + (size_t)wv * KDIM;
    for (int i0 = 0; i0 < KDIM; i0 += 512) {
      const int i = i0 + lane * 8;
      const uint4 xv = *(const uint4*)(xr + i);
      const float x0 = bf16_bits_to_f(xv.x & 0xFFFFu), x1 = bf16_bits_to_f(xv.x >> 16);
      const float x2 = bf16_bits_to_f(xv.y & 0xFFFFu), x3 = bf16_bits_to_f(xv.y >> 16);
      const float x4 = bf16_bits_to_f(xv.z & 0xFFFFu), x5 = bf16_bits_to_f(xv.z >> 16);
      const float x6 = bf16_bits_to_f(xv.w & 0xFFFFu), x7 = bf16_bits_to_f(xv.w >> 16);
#pragma unroll
      for (int t = 0; t < 12; ++t) {
        const float4 w0 = *(const float4*)(WcT + (size_t)t * 4096 + i);
        const float4 w1 = *(const float4*)(WcT + (size_t)t * 4096 + i + 4);
        acc[t] += x0 * w0.x + x1 * w0.y + x2 * w0.z + x3 * w0.w +
                  x4 * w1.x + x5 * w1.y + x6 * w1.z + x7 * w1.w;
      }
    }
  }
#pragma unroll
  for (int t = 0; t < 12; ++t)
    for (int off = 32; off > 0; off >>= 1) acc[t] += __shfl_down(acc[t], off);
  if (lane == 0) {
#pragma unroll
    for (int t = 0; t < 12; ++t) qkv[(size_t)wv * 12 + t] = acc[t];
  }
}

// ---------------------------------------------------------------------------
// K3: per-batch attention. 256 blocks: 4 batches x 64 row-blocks of 32 rows;
// 8 K-segments of 256 per row, partials combined via LDS (softmax w/o max-
// subtraction is linear in partials: l=sum e, c=sum e*v).
__global__ __launch_bounds__(256) void k_attn(const float* qkv, const void* W_o,
                                              float* a_o, const int* flagp) {
  const int flag = *flagp;
  __shared__ uint2 sk[SEQ];
  __shared__ uint2 sv[SEQ];
  __shared__ float part[8][32][9];  // seg, row, {l,c0..c3}; 9 coprime w/ 32
  const int b = blockIdx.x >> 6;    // batch 0..3
  const int rb = blockIdx.x & 63;   // row-block 0..63 (32 rows each)
  for (int j = threadIdx.x; j < SEQ; j += 256) {
    const float* qr = qkv + ((size_t)b * SEQ + j) * 12;
    uint2 pk, pv;
    pk.x = pk2(qr[4], qr[5]);
    pk.y = pk2(qr[6], qr[7]);
    pv.x = pk2(qr[8], qr[9]);
    pv.y = pk2(qr[10], qr[11]);
    sk[j] = pk;
    sv[j] = pv;
  }
  __syncthreads();
  const int row = threadIdx.x & 31;
  const int seg = threadIdx.x >> 5;  // 0..7, K-segment of 256
  const size_t m = (size_t)b * SEQ + rb * 32 + row;
  const float* qr = qkv + m * 12;
  const float q0 = qr[0] * 0.5f, q1 = qr[1] * 0.5f;  // 1/sqrt(4) folded
  const float q2 = qr[2] * 0.5f, q3 = qr[3] * 0.5f;
  float l = 0.f, c0 = 0.f, c1 = 0.f, c2 = 0.f, c3 = 0.f;
  const int j0 = seg * 256;
  for (int j = j0; j < j0 + 256; ++j) {
    const uint2 kk = sk[j];
    const float k0 = bf16_bits_to_f(kk.x & 0xFFFFu);
    const float k1 = bf16_bits_to_f(kk.x >> 16);
    const float k2 = bf16_bits_to_f(kk.y & 0xFFFFu);
    const float k3 = bf16_bits_to_f(kk.y >> 16);
    const float s = q0 * k0 + q1 * k1 + q2 * k2 + q3 * k3;
    const float e = __expf(s);
    const uint2 vv = sv[j];
    l += e;
    c0 += e * bf16_bits_to_f(vv.x & 0xFFFFu);
    c1 += e * bf16_bits_to_f(vv.x >> 16);
    c2 += e * bf16_bits_to_f(vv.y & 0xFFFFu);
    c3 += e * bf16_bits_to_f(vv.y >> 16);
  }
  part[seg][row][0] = l;
  part[seg][row][1] = c0;
  part[seg][row][2] = c1;
  part[seg][row][3] = c2;
  part[seg][row][4] = c3;
  __syncthreads();
  if (seg == 0) {
    l = 0.f; c0 = 0.f; c1 = 0.f; c2 = 0.f; c3 = 0.f;
#pragma unroll
    for (int s2 = 0; s2 < 8; ++s2) {
      l += part[s2][row][0];
      c0 += part[s2][row][1];
      c1 += part[s2][row][2];
      c2 += part[s2][row][3];
      c3 += part[s2][row][4];
    }
    const float inv = 1.0f / l;
    c0 *= inv; c1 *= inv; c2 *= inv; c3 *= inv;
    float wo[32];
#pragma unroll
    for (int i = 0; i < 32; ++i) wo[i] = dload(W_o, i, flag);
#pragma unroll
    for (int r = 0; r < 8; ++r)
      a_o[m * 8 + r] = c0 * wo[r * 4 + 0] + c1 * wo[r * 4 + 1] +
                       c2 * wo[r * 4 + 2] + c3 * wo[r * 4 + 3];
  }
}

// ---------------------------------------------------------------------------
// K4: 256x256 8-phase GEMM. Round-3 fixes vs verified round-2 schedule
// (schedule/numerics identical; only address bits changed):
//  (a) 2-bit LDS swizzle: col ^= (row bit2)*16 ^ (row bit3)*32 elements.
//      Round-2's 1-bit version left banks 16..31 idle (fk spans only half
//      the 128B row) -> structural 2-way conflict. Now 8 lanes/bank-quad
//      across all 8 quads = conflict-free ds_read_b128.
//  (b) XCD 8x8 supertile: xcd = blockIdx&7 (round-robin), its 64 concurrent
//      wgs form an 8bm x 8bn square -> per-XCD fetch = 8 A + 8 B panels
//      (32 MiB) instead of all-A (64 MiB) -> FETCH ~543->~300 MB.
__global__ __launch_bounds__(512, 2) void k_gemm8(
    const void* x, const void* w, const uint16_t* xb, const uint16_t* wb,
    const float* a_o, const float* W_up_s, const float* b_pre_f, void* out,
    const int* flagp) {
  const int flag = *flagp;
  const uint16_t* Ag = flag ? (const uint16_t*)x : xb;
  const uint16_t* Bg = flag ? (const uint16_t*)w : wb;
  __shared__ __align__(16) uint16_t smem[2][2][16384];  // [buf][A/B][256*64]

  const int t = threadIdx.x;
  const int lane = t & 63;
  const int wid = t >> 6;
  // XCD-aware 8x8 supertile mapping (bijective over 512 wgs)
  const int xcd = (int)blockIdx.x & 7;
  const int j = (int)blockIdx.x >> 3;          // 0..63 within XCD
  const int bm = (xcd & 3) * 8 + (j & 7);      // 32 m-tiles (M=8192)
  const int bn = (xcd >> 2) * 8 + (j >> 3);    // 16 n-tiles (N=4096)

  // staging map: call c, wave wid, lane -> row c*64+wid*8+(lane>>3),
  // col ((lane&7)*8) ^ swz(row), swz(r) = (r>>2&1)*16 ^ (r>>3&1)*32 elems
  const int sr0 = 0 * 64 + wid * 8 + (lane >> 3);
  const int sr1 = 1 * 64 + wid * 8 + (lane >> 3);
  const int sc0 = ((lane & 7) * 8) ^ (((sr0 >> 2) & 1) * 16) ^
                  (((sr0 >> 3) & 1) * 32);
  const int sc1 = ((lane & 7) * 8) ^ (((sr1 >> 2) & 1) * 16) ^
                  (((sr1 >> 3) & 1) * 32);
  const size_t aoff0 = (size_t)(bm * 256 + sr0) * KDIM + sc0;
  const size_t aoff1 = (size_t)(bm * 256 + sr1) * KDIM + sc1;
  const size_t boff0 = (size_t)(bn * 256 + sr0) * KDIM + sc0;
  const size_t boff1 = (size_t)(bn * 256 + sr1) * KDIM + sc1;

  // wave/fragment map
  const int wn_idx = wid & 3;
  const int wm_idx = wid >> 2;
  const int wave_m0 = wm_idx * 128;  // rows within 256-tile
  const int wave_n0 = wn_idx * 64;   // cols within 256-tile
  const int fr = lane & 15;
  // swizzled k-offset: fk ^ swz(fragment row); frag row bits 2,3 = fr bits
  const int fkbe = ((lane >> 4) * 8) ^ (((lane >> 2) & 1) * 16) ^
                   (((lane >> 3) & 1) * 32);

  f32x4 acc[8][4];
#pragma unroll
  for (int a = 0; a < 8; ++a)
#pragma unroll
    for (int b = 0; b < 4; ++b) acc[a][b] = (f32x4){0.f, 0.f, 0.f, 0.f};

  short8 a_reg[4][2];     // current m-half: 4 m-frags x 2 k-halves
  short8 b_reg[2][2][2];  // all B: [n-half][n-frag][k-half]

#define STAGE(BUF, OP, H, TILE)                                               \
  do {                                                                        \
    const uint16_t* g_ = (OP) ? Bg : Ag;                                      \
    const size_t ho_ = (size_t)(H) * (128 * KDIM) + (size_t)(TILE) * 64;      \
    gld_lds16(g_ + ((OP) ? boff0 : aoff0) + ho_,                              \
              &smem[BUF][OP][(H) * 8192 + wid * 512]);                        \
    gld_lds16(g_ + ((OP) ? boff1 : aoff1) + ho_,                              \
              &smem[BUF][OP][(H) * 8192 + 4096 + wid * 512]);                 \
  } while (0)

#define A_LOAD(BUF, MH)                                                       \
  do {                                                                        \
    _Pragma("unroll") for (int f = 0; f < 4; ++f) {                           \
      a_reg[f][0] = *(const short8*)&smem[BUF][0][                            \
          (wave_m0 + ((MH)*4 + f) * 16 + fr) * 64 + fkbe];                    \
      a_reg[f][1] = *(const short8*)&smem[BUF][0][                            \
          (wave_m0 + ((MH)*4 + f) * 16 + fr) * 64 + (fkbe ^ 32)];             \
    }                                                                         \
  } while (0)

#define B_LOAD(BUF, NH)                                                       \
  do {                                                                        \
    _Pragma("unroll") for (int g = 0; g < 2; ++g) {                           \
      b_reg[NH][g][0] = *(const short8*)&smem[BUF][1][                        \
          (wave_n0 + ((NH)*2 + g) * 16 + fr) * 64 + fkbe];                    \
      b_reg[NH][g][1] = *(const short8*)&smem[BUF][1][                        \
          (wave_n0 + ((NH)*2 + g) * 16 + fr) * 64 + (fkbe ^ 32)];             \
    }                                                                         \
  } while (0)

#define MFMA_Q(MH, NH)                                                        \
  do {                                                                        \
    __builtin_amdgcn_s_setprio(1);                                            \
    _Pragma("unroll") for (int f = 0; f < 4; ++f) {                           \
      _Pragma("unroll") for (int g = 0; g < 2; ++g) {                         \
        acc[(MH)*4 + f][(NH)*2 + g] = __builtin_amdgcn_mfma_f32_16x16x32_bf16(\
            a_reg[f][0], b_reg[NH][g][0], acc[(MH)*4 + f][(NH)*2 + g], 0,0,0);\
        acc[(MH)*4 + f][(NH)*2 + g] = __builtin_amdgcn_mfma_f32_16x16x32_bf16(\
            a_reg[f][1], b_reg[NH][g][1], acc[(MH)*4 + f][(NH)*2 + g], 0,0,0);\
      }                                                                       \
    }                                                                         \
    __builtin_amdgcn_s_setprio(0);                                            \
  } while (0)

  // Prologue: t0 full (buf0) + t1.B0,B1 (buf1) = 12 loads; wait t0 landed.
  STAGE(0, 0, 0, 0); STAGE(0, 0, 1, 0); STAGE(0, 1, 0, 0); STAGE(0, 1, 1, 0);
  STAGE(1, 1, 0, 1); STAGE(1, 1, 1, 1);
  VMCNT4();
  BARRIER();

#pragma unroll 1
  for (int it = 0; it < 31; ++it) {
    const int tO = 2 * it + 1, tE2 = 2 * it + 2, tO2 = 2 * it + 3;
    // ph0
    A_LOAD(0, 0); B_LOAD(0, 0); STAGE(1, 0, 0, tO);
    BARRIER(); MFMA_Q(0, 0); BARRIER();
    // ph1
    B_LOAD(0, 1); STAGE(1, 0, 1, tO);
    BARRIER(); MFMA_Q(0, 1); BARRIER();
    // ph2
    A_LOAD(0, 1); STAGE(0, 1, 0, tE2);
    BARRIER(); MFMA_Q(1, 0); BARRIER();
    // ph3
    STAGE(0, 1, 1, tE2);
    BARRIER(); MFMA_Q(1, 1); VMCNT4(); BARRIER();
    // ph4
    A_LOAD(1, 0); B_LOAD(1, 0); STAGE(0, 0, 0, tE2);
    BARRIER(); MFMA_Q(0, 0); BARRIER();
    // ph5
    B_LOAD(1, 1); STAGE(0, 0, 1, tE2);
    BARRIER(); MFMA_Q(0, 1); BARRIER();
    // ph6
    A_LOAD(1, 1); STAGE(1, 1, 0, tO2);
    BARRIER(); MFMA_Q(1, 0); BARRIER();
    // ph7
    STAGE(1, 1, 1, tO2);
    BARRIER(); MFMA_Q(1, 1); VMCNT4(); BARRIER();
  }
  // Tail: tiles 62 (buf0), 63 (buf1). Stage only 63.A0/A1; drain at ph3.
  A_LOAD(0, 0); B_LOAD(0, 0); STAGE(1, 0, 0, 63);
  BARRIER(); MFMA_Q(0, 0); BARRIER();
  B_LOAD(0, 1); STAGE(1, 0, 1, 63);
  BARRIER(); MFMA_Q(0, 1); BARRIER();
  A_LOAD(0, 1);
  BARRIER(); MFMA_Q(1, 0); BARRIER();
  BARRIER(); MFMA_Q(1, 1); VMCNT0(); BARRIER();
  A_LOAD(1, 0); B_LOAD(1, 0);
  BARRIER(); MFMA_Q(0, 0); BARRIER();
  B_LOAD(1, 1);
  BARRIER(); MFMA_Q(0, 1); BARRIER();
  A_LOAD(1, 1);
  BARRIER(); MFMA_Q(1, 0); BARRIER();
  BARRIER(); MFMA_Q(1, 1); BARRIER();

  // Epilogue. C/D map (verified): col = lane&15, row = (lane>>4)*4 + reg.
  const int rq = (lane >> 4) * 4;
  float4 u0r[4], u1r[4];
  float bpr[4];
#pragma unroll
  for (int nf = 0; nf < 4; ++nf) {
    const int gn = bn * 256 + wave_n0 + nf * 16 + fr;
    bpr[nf] = b_pre_f[gn];
    u0r[nf] = *(const float4*)&W_up_s[(size_t)gn * 8];
    u1r[nf] = *(const float4*)&W_up_s[(size_t)gn * 8 + 4];
  }
#pragma unroll
  for (int mf = 0; mf < 8; ++mf) {
#pragma unroll
    for (int r = 0; r < 4; ++r) {
      const int gm = bm * 256 + wave_m0 + mf * 16 + rq + r;
      const float4 a0 = *(const float4*)&a_o[(size_t)gm * 8];
      const float4 a1 = *(const float4*)&a_o[(size_t)gm * 8 + 4];
#pragma unroll
      for (int nf = 0; nf < 4; ++nf) {
        const int gn = bn * 256 + wave_n0 + nf * 16 + fr;
        float v = acc[mf][nf][r] + bpr[nf] +
                  a0.x * u0r[nf].x + a0.y * u0r[nf].y + a0.z * u0r[nf].z +
                  a0.w * u0r[nf].w + a1.x * u1r[nf].x + a1.y * u1r[nf].y +
                  a1.z * u1r[nf].z + a1.w * u1r[nf].w;
        const size_t oidx = (size_t)gm * NDIM + gn;
        if (flag) ((uint16_t*)out)[oidx] = f2b(v);
        else ((float*)out)[oidx] = v;
      }
    }
  }
#undef STAGE
#undef A_LOAD
#undef B_LOAD
#undef MFMA_Q
}

// ---------------------------------------------------------------------------
// K4 fallback (verified round 0): only if workspace too small for bf16 copies.
__global__ __launch_bounds__(256) void k_gemm_fb(
    const void* x, const void* w, const float* a_o, const float* W_up_s,
    const float* b_pre_f, void* out, const int* flagp) {
  const int flag = *flagp;
  __shared__ __align__(16) uint16_t sA[128 * 64];
  __shared__ __align__(16) uint16_t sB[128 * 64];
  const int t = threadIdx.x;
  const int bm = blockIdx.x & 63;
  const int bn = blockIdx.x >> 6;
  const int srow = t >> 1;
  const int scol = (t & 1) * 32;
  const size_t ga = ((size_t)(bm * 128 + srow)) * KDIM + scol;
  const size_t gb = ((size_t)(bn * 128 + srow)) * KDIM + scol;
  const int lane = t & 63;
  const int wid = t >> 6;
  const int wm = (wid & 1) * 64;
  const int wn = (wid >> 1) * 64;
  const int fr = lane & 15;
  const int fk = (lane >> 4) * 8;
  f32x4 acc[4][4];
#pragma unroll
  for (int a = 0; a < 4; ++a)
#pragma unroll
    for (int bq = 0; bq < 4; ++bq) acc[a][bq] = (f32x4){0.f, 0.f, 0.f, 0.f};

  for (int k0 = 0; k0 < KDIM; k0 += 64) {
    __syncthreads();
    if (flag) {
      const uint16_t* gx = (const uint16_t*)x + ga + k0;
      const uint16_t* gw = (const uint16_t*)w + gb + k0;
#pragma unroll
      for (int c = 0; c < 4; ++c) {
        *(uint4*)&sA[srow * 64 + scol + c * 8] = *(const uint4*)(gx + c * 8);
        *(uint4*)&sB[srow * 64 + scol + c * 8] = *(const uint4*)(gw + c * 8);
      }
    } else {
      const float* gx = (const float*)x + ga + k0;
      const float* gw = (const float*)w + gb + k0;
#pragma unroll
      for (int c = 0; c < 4; ++c) {
        float4 xa = *(const float4*)(gx + c * 8);
        float4 xb2 = *(const float4*)(gx + c * 8 + 4);
        uint4 pk;
        pk.x = pk2(xa.x, xa.y);
        pk.y = pk2(xa.z, xa.w);
        pk.z = pk2(xb2.x, xb2.y);
        pk.w = pk2(xb2.z, xb2.w);
        *(uint4*)&sA[srow * 64 + scol + c * 8] = pk;
        float4 wa = *(const float4*)(gw + c * 8);
        float4 wb2 = *(const float4*)(gw + c * 8 + 4);
        uint4 pw;
        pw.x = pk2(wa.x, wa.y);
        pw.y = pk2(wa.z, wa.w);
        pw.z = pk2(wb2.x, wb2.y);
        pw.w = pk2(wb2.z, wb2.w);
        *(uint4*)&sB[srow * 64 + scol + c * 8] = pw;
      }
    }
    __syncthreads();
#pragma unroll
    for (int kk = 0; kk < 64; kk += 32) {
      short8 af[4], bfr[4];
#pragma unroll
      for (int mb = 0; mb < 4; ++mb)
        af[mb] = *(const short8*)&sA[(wm + mb * 16 + fr) * 64 + kk + fk];
#pragma unroll
      for (int nb = 0; nb < 4; ++nb)
        bfr[nb] = *(const short8*)&sB[(wn + nb * 16 + fr) * 64 + kk + fk];
#pragma unroll
      for (int mb = 0; mb < 4; ++mb)
#pragma unroll
        for (int nb = 0; nb < 4; ++nb)
          acc[mb][nb] = __builtin_amdgcn_mfma_f32_16x16x32_bf16(
              af[mb], bfr[nb], acc[mb][nb], 0, 0, 0);
    }
  }
  const int rq = (lane >> 4) * 4;
#pragma unroll
  for (int nb = 0; nb < 4; ++nb) {
    const int gn = bn * 128 + wn + nb * 16 + fr;
    const float bp = b_pre_f[gn];
    const float4 u0 = *(const float4*)&W_up_s[(size_t)gn * 8];
    const float4 u1 = *(const float4*)&W_up_s[(size_t)gn * 8 + 4];
#pragma unroll
    for (int mb = 0; mb < 4; ++mb) {
#pragma unroll
      for (int r = 0; r < 4; ++r) {
        const int gm = bm * 128 + wm + mb * 16 + rq + r;
        const float4 a0 = *(const float4*)&a_o[(size_t)gm * 8];
        const float4 a1 = *(const float4*)&a_o[(size_t)gm * 8 + 4];
        float v = acc[mb][nb][r] + bp + a0.x * u0.x + a0.y * u0.y +
                  a0.z * u0.z + a0.w * u0.w + a1.x * u1.x + a1.y * u1.y +
                  a1.z * u1.z + a1.w * u1.w;
        const size_t oidx = (size_t)gm * NDIM + gn;
        if (flag) ((uint16_t*)out)[oidx] = f2b(v);
        else ((float*)out)[oidx] = v;
      }
    }
  }
}

// ---------------------------------------------------------------------------
extern "C" void kernel_launch(void* const* d_in, const int* in_sizes, int n_in,
                              void* d_out, int out_size, void* d_ws,
                              size_t ws_size, hipStream_t stream) {
  const void* x = d_in[0];
  const void* W_pre = d_in[1];
  const void* b_pre = d_in[2];
  const void* W_down = d_in[3];
  const void* W_qkv = d_in[4];
  const void* W_o = d_in[5];
  const void* W_up = d_in[6];
  const void* diag_b = d_in[7];

  char* ws = (char*)d_ws;
  int* flag_p = (int*)ws;                        // @0
  float* WcT = (float*)(ws + 256);               // [12][4096] f32
  float* qkv = (float*)(ws + 196864);            // [8192][12] f32
  float* a_o = (float*)(ws + 590080);            // [8192][8]  f32
  float* W_up_s = (float*)(ws + 852224);         // [4096][8]  f32
  float* b_pre_f = (float*)(ws + 983296);        // [4096]     f32
  uint16_t* xb = (uint16_t*)(ws + 1048576);      // [8192][4096] bf16, 64 MiB
  uint16_t* wb = (uint16_t*)(ws + 68157440);     // [4096][4096] bf16, 32 MiB
  const bool big = ws_size >= (size_t)101711872;

  k_detect<<<1, 64, 0, stream>>>((const uint16_t*)x, flag_p);
  k_prep<<<192, 256, 0, stream>>>(W_down, W_qkv, W_up, diag_b, b_pre, WcT,
                                  W_up_s, b_pre_f, flag_p);
  k_qkvconv<<<2560, 256, 0, stream>>>(x, WcT, qkv, xb, W_pre, wb,
                                      big ? 1 : 0, flag_p);
  k_attn<<<256, 256, 0, stream>>>(qkv, W_o, a_o, flag_p);
  if (big)
    k_gemm8<<<512, 512, 0, stream>>>(x, W_pre, xb, wb, a_o, W_up_s, b_pre_f,
                                     d_out, flag_p);
  else
    k_gemm_fb<<<2048, 256, 0, stream>>>(x, W_pre, a_o, W_up_s, b_pre_f, d_out,
                                        flag_p);
}

// Round 4
// 597.539 us; speedup vs baseline: 2.7359x; 1.0006x over previous
//
#include <hip/hip_runtime.h>
#include <stdint.h>

// Problem constants
#define KDIM 4096   // IN_DIM
#define NDIM 4096   // OUT_DIM
#define MROWS 8192  // 4*2048
#define SEQ 2048

typedef __attribute__((ext_vector_type(8))) short short8;
typedef __attribute__((ext_vector_type(4))) float f32x4;

__device__ __forceinline__ float bf16_bits_to_f(uint32_t u16) {
  union { uint32_t u; float f; } c; c.u = u16 << 16; return c.f;
}
__device__ __forceinline__ float dload(const void* p, size_t idx, int flag) {
  if (flag) return bf16_bits_to_f(((const uint16_t*)p)[idx]);
  return ((const float*)p)[idx];
}
__device__ __forceinline__ uint16_t f2b(float f) {  // RNE f32->bf16
  union { float f; uint32_t u; } c; c.f = f;
  uint32_t b = c.u;
  return (uint16_t)((b + 0x7FFFu + ((b >> 16) & 1u)) >> 16);
}
__device__ __forceinline__ uint32_t pk2(float a, float b) {
  return (uint32_t)f2b(a) | ((uint32_t)f2b(b) << 16);
}
// async global->LDS, 16B per lane. LDS dest = wave-uniform base + lane*16.
__device__ __forceinline__ void gld_lds16(const uint16_t* g, uint16_t* l) {
  __builtin_amdgcn_global_load_lds(
      (const __attribute__((address_space(1))) uint32_t*)g,
      (__attribute__((address_space(3))) uint32_t*)l, 16, 0, 0);
}

#define BARRIER() asm volatile("s_barrier" ::: "memory")
#define VMCNT0() asm volatile("s_waitcnt vmcnt(0)" ::: "memory")

// ---------------------------------------------------------------------------
// K0: dtype detection (verified). flag=1 means bf16 storage.
__global__ void k_detect(const uint16_t* xu, int* flag) {
  int lane = threadIdx.x;
  int bad = 0;
  for (int i = lane; i < 512; i += 64) {
    float v = bf16_bits_to_f((uint32_t)xu[i]);
    if (!(v == v) || fabsf(v) > 1000.0f) bad++;
  }
  for (int off = 32; off > 0; off >>= 1) bad += __shfl_down(bad, off);
  if (lane == 0) *flag = (bad < 32) ? 1 : 0;
}

// ---------------------------------------------------------------------------
// K1: tiny precomputes (verified).
__global__ __launch_bounds__(256) void k_prep(
    const void* W_down, const void* W_qkv, const void* W_up,
    const void* diag_b, const void* b_pre,
    float* WcT, float* W_up_s, float* b_pre_f, const int* flagp) {
  const int flag = *flagp;
  const int tid = blockIdx.x * 256 + threadIdx.x;
  const int tt = tid >> 12;
  const int i = tid & 4095;
  float s = 0.f;
#pragma unroll
  for (int r = 0; r < 8; ++r)
    s += dload(W_qkv, tt * 8 + r, flag) * dload(W_down, (size_t)r * 4096 + i, flag);
  WcT[(size_t)tt * 4096 + i] = s;
  if (tid < 32768)
    W_up_s[tid] = dload(W_up, tid, flag) * dload(diag_b, tid >> 3, flag) * 4.0f;
  if (tid < 4096)
    b_pre_f[tid] = dload(b_pre, tid, flag);
}

// ---------------------------------------------------------------------------
// K2: fused qkv + x->bf16 conversion (blocks < 2048) and W_pre->bf16
// conversion (blocks 2048..2559). Both memory-bound, run concurrently.
__global__ __launch_bounds__(256) void k_qkvconv(
    const void* x, const float* WcT, float* qkv, uint16_t* xb,
    const void* W_pre, uint16_t* wb, int do_conv, const int* flagp) {
  const int flag = *flagp;
  if (blockIdx.x >= 2048) {
    if (flag || !do_conv) return;
    const float* w = (const float*)W_pre;
    const size_t n = (size_t)NDIM * KDIM;
    const size_t stride = (size_t)512 * 256 * 8;
    for (size_t idx = (((size_t)blockIdx.x - 2048) * 256 + threadIdx.x) * 8;
         idx < n; idx += stride) {
      const float4 a = *(const float4*)(w + idx);
      const float4 b = *(const float4*)(w + idx + 4);
      uint4 p;
      p.x = pk2(a.x, a.y);
      p.y = pk2(a.z, a.w);
      p.z = pk2(b.x, b.y);
      p.w = pk2(b.z, b.w);
      *(uint4*)(wb + idx) = p;
    }
    return;
  }
  const int wv = (int)((blockIdx.x * 256 + threadIdx.x) >> 6);  // row 0..8191
  const int lane = threadIdx.x & 63;
  float acc[12];
#pragma unroll
  for (int t = 0; t < 12; ++t) acc[t] = 0.f;
  if (!flag) {
    const float* xr = (const float*)x + (size_t)wv * KDIM;
    uint16_t* xo = xb + (size_t)wv * KDIM;
    for (int i0 = 0; i0 < KDIM; i0 += 256) {
      const int i = i0 + lane * 4;
      const float4 xv = *(const float4*)(xr + i);
      if (do_conv) {
        uint2 p;
        p.x = pk2(xv.x, xv.y);
        p.y = pk2(xv.z, xv.w);
        *(uint2*)(xo + i) = p;
      }
#pragma unroll
      for (int t = 0; t < 12; ++t) {
        const float4 w4 = *(const float4*)(WcT + (size_t)t * 4096 + i);
        acc[t] += xv.x * w4.x + xv.y * w4.y + xv.z * w4.z + xv.w * w4.w;
      }
    }
  } else {
    const uint16_t* xr = (const uint16_t*)x + (size_t)wv * KDIM;
    for (int i0 = 0; i0 < KDIM; i0 += 512) {
      const int i = i0 + lane * 8;
      const uint4 xv = *(const uint4*)(xr + i);
      const float x0 = bf16_bits_to_f(xv.x & 0xFFFFu), x1 = bf16_bits_to_f(xv.x >> 16);
      const float x2 = bf16_bits_to_f(xv.y & 0xFFFFu), x3 = bf16_bits_to_f(xv.y >> 16);
      const float x4 = bf16_bits_to_f(xv.z & 0xFFFFu), x5 = bf16_bits_to_f(xv.z >> 16);
      const float x6 = bf16_bits_to_f(xv.w & 0xFFFFu), x7 = bf16_bits_to_f(xv.w >> 16);
#pragma unroll
      for (int t = 0; t < 12; ++t) {
        const float4 w0 = *(const float4*)(WcT + (size_t)t * 4096 + i);
        const float4 w1 = *(const float4*)(WcT + (size_t)t * 4096 + i + 4);
        acc[t] += x0 * w0.x + x1 * w0.y + x2 * w0.z + x3 * w0.w +
                  x4 * w1.x + x5 * w1.y + x6 * w1.z + x7 * w1.w;
      }
    }
  }
#pragma unroll
  for (int t = 0; t < 12; ++t)
    for (int off = 32; off > 0; off >>= 1) acc[t] += __shfl_down(acc[t], off);
  if (lane == 0) {
#pragma unroll
    for (int t = 0; t < 12; ++t) qkv[(size_t)wv * 12 + t] = acc[t];
  }
}

// ---------------------------------------------------------------------------
// K3: per-batch attention (verified round 3).
__global__ __launch_bounds__(256) void k_attn(const float* qkv, const void* W_o,
                                              float* a_o, const int* flagp) {
  const int flag = *flagp;
  __shared__ uint2 sk[SEQ];
  __shared__ uint2 sv[SEQ];
  __shared__ float part[8][32][9];
  const int b = blockIdx.x >> 6;
  const int rb = blockIdx.x & 63;
  for (int j = threadIdx.x; j < SEQ; j += 256) {
    const float* qr = qkv + ((size_t)b * SEQ + j) * 12;
    uint2 pk, pv;
    pk.x = pk2(qr[4], qr[5]);
    pk.y = pk2(qr[6], qr[7]);
    pv.x = pk2(qr[8], qr[9]);
    pv.y = pk2(qr[10], qr[11]);
    sk[j] = pk;
    sv[j] = pv;
  }
  __syncthreads();
  const int row = threadIdx.x & 31;
  const int seg = threadIdx.x >> 5;
  const size_t m = (size_t)b * SEQ + rb * 32 + row;
  const float* qr = qkv + m * 12;
  const float q0 = qr[0] * 0.5f, q1 = qr[1] * 0.5f;
  const float q2 = qr[2] * 0.5f, q3 = qr[3] * 0.5f;
  float l = 0.f, c0 = 0.f, c1 = 0.f, c2 = 0.f, c3 = 0.f;
  const int j0 = seg * 256;
  for (int j = j0; j < j0 + 256; ++j) {
    const uint2 kk = sk[j];
    const float k0 = bf16_bits_to_f(kk.x & 0xFFFFu);
    const float k1 = bf16_bits_to_f(kk.x >> 16);
    const float k2 = bf16_bits_to_f(kk.y & 0xFFFFu);
    const float k3 = bf16_bits_to_f(kk.y >> 16);
    const float s = q0 * k0 + q1 * k1 + q2 * k2 + q3 * k3;
    const float e = __expf(s);
    const uint2 vv = sv[j];
    l += e;
    c0 += e * bf16_bits_to_f(vv.x & 0xFFFFu);
    c1 += e * bf16_bits_to_f(vv.x >> 16);
    c2 += e * bf16_bits_to_f(vv.y & 0xFFFFu);
    c3 += e * bf16_bits_to_f(vv.y >> 16);
  }
  part[seg][row][0] = l;
  part[seg][row][1] = c0;
  part[seg][row][2] = c1;
  part[seg][row][3] = c2;
  part[seg][row][4] = c3;
  __syncthreads();
  if (seg == 0) {
    l = 0.f; c0 = 0.f; c1 = 0.f; c2 = 0.f; c3 = 0.f;
#pragma unroll
    for (int s2 = 0; s2 < 8; ++s2) {
      l += part[s2][row][0];
      c0 += part[s2][row][1];
      c1 += part[s2][row][2];
      c2 += part[s2][row][3];
      c3 += part[s2][row][4];
    }
    const float inv = 1.0f / l;
    c0 *= inv; c1 *= inv; c2 *= inv; c3 *= inv;
    float wo[32];
#pragma unroll
    for (int i = 0; i < 32; ++i) wo[i] = dload(W_o, i, flag);
#pragma unroll
    for (int r = 0; r < 8; ++r)
      a_o[m * 8 + r] = c0 * wo[r * 4 + 0] + c1 * wo[r * 4 + 1] +
                       c2 * wo[r * 4 + 2] + c3 * wo[r * 4 + 3];
  }
}

// ---------------------------------------------------------------------------
// K4: 256x256 GEMM, round 4: cross-buffer ledger, 1 barrier per K-tile.
// During tile t (buf b): stage ALL of tile t+1 into buf b^1 (b^1's last reads
// finished before the previous tile's barrier -> unconditionally race-free),
// then one big compiler-scheduled region: 24 ds_read_b128 + 64 MFMA.
// vmcnt(0) at tile end waits on loads issued ~1 tile earlier (=free), then
// s_barrier. Removes the 8-phase lockstep that serialized LDS service vs
// MFMA (r3: 1240 cyc/phase ~= 620 MFMA + 620 LDS/sync, MfmaUtil 42%).
// MFMA order per acc element unchanged -> bit-identical numerics vs r3.
__global__ __launch_bounds__(512, 2) void k_gemm8(
    const void* x, const void* w, const uint16_t* xb, const uint16_t* wb,
    const float* a_o, const float* W_up_s, const float* b_pre_f, void* out,
    const int* flagp) {
  const int flag = *flagp;
  const uint16_t* Ag = flag ? (const uint16_t*)x : xb;
  const uint16_t* Bg = flag ? (const uint16_t*)w : wb;
  __shared__ __align__(16) uint16_t smem[2][2][16384];  // [buf][A/B][256*64]

  const int t = threadIdx.x;
  const int lane = t & 63;
  const int wid = t >> 6;
  // XCD-aware 8x8 supertile mapping (bijective over 512 wgs) — verified r3
  const int xcd = (int)blockIdx.x & 7;
  const int j = (int)blockIdx.x >> 3;          // 0..63 within XCD
  const int bm = (xcd & 3) * 8 + (j & 7);      // 32 m-tiles (M=8192)
  const int bn = (xcd >> 2) * 8 + (j >> 3);    // 16 n-tiles (N=4096)

  // staging map: call c, wave wid, lane -> row c*64+wid*8+(lane>>3),
  // col ((lane&7)*8) ^ swz(row), swz(r) = (r>>2&1)*16 ^ (r>>3&1)*32 elems
  const int sr0 = 0 * 64 + wid * 8 + (lane >> 3);
  const int sr1 = 1 * 64 + wid * 8 + (lane >> 3);
  const int sc0 = ((lane & 7) * 8) ^ (((sr0 >> 2) & 1) * 16) ^
                  (((sr0 >> 3) & 1) * 32);
  const int sc1 = ((lane & 7) * 8) ^ (((sr1 >> 2) & 1) * 16) ^
                  (((sr1 >> 3) & 1) * 32);
  const size_t aoff0 = (size_t)(bm * 256 + sr0) * KDIM + sc0;
  const size_t aoff1 = (size_t)(bm * 256 + sr1) * KDIM + sc1;
  const size_t boff0 = (size_t)(bn * 256 + sr0) * KDIM + sc0;
  const size_t boff1 = (size_t)(bn * 256 + sr1) * KDIM + sc1;

  // wave/fragment map
  const int wn_idx = wid & 3;
  const int wm_idx = wid >> 2;
  const int wave_m0 = wm_idx * 128;  // rows within 256-tile
  const int wave_n0 = wn_idx * 64;   // cols within 256-tile
  const int fr = lane & 15;
  // swizzled k-offset: fk ^ swz(fragment row); frag row bits 2,3 = fr bits
  const int fkbe = ((lane >> 4) * 8) ^ (((lane >> 2) & 1) * 16) ^
                   (((lane >> 3) & 1) * 32);

  f32x4 acc[8][4];
#pragma unroll
  for (int a = 0; a < 8; ++a)
#pragma unroll
    for (int b = 0; b < 4; ++b) acc[a][b] = (f32x4){0.f, 0.f, 0.f, 0.f};

  short8 a_reg[4][2];     // current m-half: 4 m-frags x 2 k-halves
  short8 b_reg[2][2][2];  // all B: [n-half][n-frag][k-half]

#define STAGE(BUF, OP, H, TILE)                                               \
  do {                                                                        \
    const uint16_t* g_ = (OP) ? Bg : Ag;                                      \
    const size_t ho_ = (size_t)(H) * (128 * KDIM) + (size_t)(TILE) * 64;      \
    gld_lds16(g_ + ((OP) ? boff0 : aoff0) + ho_,                              \
              &smem[BUF][OP][(H) * 8192 + wid * 512]);                        \
    gld_lds16(g_ + ((OP) ? boff1 : aoff1) + ho_,                              \
              &smem[BUF][OP][(H) * 8192 + 4096 + wid * 512]);                 \
  } while (0)

#define A_LOAD(BUF, MH)                                                       \
  do {                                                                        \
    _Pragma("unroll") for (int f = 0; f < 4; ++f) {                           \
      a_reg[f][0] = *(const short8*)&smem[BUF][0][                            \
          (wave_m0 + ((MH)*4 + f) * 16 + fr) * 64 + fkbe];                    \
      a_reg[f][1] = *(const short8*)&smem[BUF][0][                            \
          (wave_m0 + ((MH)*4 + f) * 16 + fr) * 64 + (fkbe ^ 32)];             \
    }                                                                         \
  } while (0)

#define B_LOAD(BUF, NH)                                                       \
  do {                                                                        \
    _Pragma("unroll") for (int g = 0; g < 2; ++g) {                           \
      b_reg[NH][g][0] = *(const short8*)&smem[BUF][1][                        \
          (wave_n0 + ((NH)*2 + g) * 16 + fr) * 64 + fkbe];                    \
      b_reg[NH][g][1] = *(const short8*)&smem[BUF][1][                        \
          (wave_n0 + ((NH)*2 + g) * 16 + fr) * 64 + (fkbe ^ 32)];             \
    }                                                                         \
  } while (0)

#define MFMA_Q(MH, NH)                                                        \
  do {                                                                        \
    __builtin_amdgcn_s_setprio(1);                                            \
    _Pragma("unroll") for (int f = 0; f < 4; ++f) {                           \
      _Pragma("unroll") for (int g = 0; g < 2; ++g) {                         \
        acc[(MH)*4 + f][(NH)*2 + g] = __builtin_amdgcn_mfma_f32_16x16x32_bf16(\
            a_reg[f][0], b_reg[NH][g][0], acc[(MH)*4 + f][(NH)*2 + g], 0,0,0);\
        acc[(MH)*4 + f][(NH)*2 + g] = __builtin_amdgcn_mfma_f32_16x16x32_bf16(\
            a_reg[f][1], b_reg[NH][g][1], acc[(MH)*4 + f][(NH)*2 + g], 0,0,0);\
      }                                                                       \
    }                                                                         \
    __builtin_amdgcn_s_setprio(0);                                            \
  } while (0)

// One K-tile: optional stage of tile TT+1 into buf B^1 (issued first for max
// latency hiding), then the compute region, then vmcnt(0)+barrier.
#define TILE_BODY(B, TT, DOSTAGE)                                             \
  do {                                                                        \
    if (DOSTAGE) {                                                            \
      STAGE(B ^ 1, 0, 0, (TT) + 1);                                           \
      STAGE(B ^ 1, 0, 1, (TT) + 1);                                           \
      STAGE(B ^ 1, 1, 0, (TT) + 1);                                           \
      STAGE(B ^ 1, 1, 1, (TT) + 1);                                           \
    }                                                                         \
    A_LOAD(B, 0); B_LOAD(B, 0); MFMA_Q(0, 0);                                 \
    B_LOAD(B, 1); MFMA_Q(0, 1);                                               \
    A_LOAD(B, 1); MFMA_Q(1, 0);                                               \
    MFMA_Q(1, 1);                                                             \
    VMCNT0();                                                                 \
    BARRIER();                                                                \
  } while (0)

  // Prologue: stage tile 0 into buf0, wait, sync.
  STAGE(0, 0, 0, 0); STAGE(0, 0, 1, 0); STAGE(0, 1, 0, 0); STAGE(0, 1, 1, 0);
  VMCNT0();
  BARRIER();

#pragma unroll 1
  for (int it = 0; it < 31; ++it) {
    TILE_BODY(0, 2 * it, 1);
    TILE_BODY(1, 2 * it + 1, 1);
  }
  TILE_BODY(0, 62, 1);
  TILE_BODY(1, 63, 0);

  // Epilogue. C/D map (verified): col = lane&15, row = (lane>>4)*4 + reg.
  const int rq = (lane >> 4) * 4;
  float4 u0r[4], u1r[4];
  float bpr[4];
#pragma unroll
  for (int nf = 0; nf < 4; ++nf) {
    const int gn = bn * 256 + wave_n0 + nf * 16 + fr;
    bpr[nf] = b_pre_f[gn];
    u0r[nf] = *(const float4*)&W_up_s[(size_t)gn * 8];
    u1r[nf] = *(const float4*)&W_up_s[(size_t)gn * 8 + 4];
  }
#pragma unroll
  for (int mf = 0; mf < 8; ++mf) {
#pragma unroll
    for (int r = 0; r < 4; ++r) {
      const int gm = bm * 256 + wave_m0 + mf * 16 + rq + r;
      const float4 a0 = *(const float4*)&a_o[(size_t)gm * 8];
      const float4 a1 = *(const float4*)&a_o[(size_t)gm * 8 + 4];
#pragma unroll
      for (int nf = 0; nf < 4; ++nf) {
        const int gn = bn * 256 + wave_n0 + nf * 16 + fr;
        float v = acc[mf][nf][r] + bpr[nf] +
                  a0.x * u0r[nf].x + a0.y * u0r[nf].y + a0.z * u0r[nf].z +
                  a0.w * u0r[nf].w + a1.x * u1r[nf].x + a1.y * u1r[nf].y +
                  a1.z * u1r[nf].z + a1.w * u1r[nf].w;
        const size_t oidx = (size_t)gm * NDIM + gn;
        if (flag) ((uint16_t*)out)[oidx] = f2b(v);
        else ((float*)out)[oidx] = v;
      }
    }
  }
#undef TILE_BODY
#undef STAGE
#undef A_LOAD
#undef B_LOAD
#undef MFMA_Q
}

// ---------------------------------------------------------------------------
// K4 fallback (verified round 0): only if workspace too small for bf16 copies.
__global__ __launch_bounds__(256) void k_gemm_fb(
    const void* x, const void* w, const float* a_o, const float* W_up_s,
    const float* b_pre_f, void* out, const int* flagp) {
  const int flag = *flagp;
  __shared__ __align__(16) uint16_t sA[128 * 64];
  __shared__ __align__(16) uint16_t sB[128 * 64];
  const int t = threadIdx.x;
  const int bm = blockIdx.x & 63;
  const int bn = blockIdx.x >> 6;
  const int srow = t >> 1;
  const int scol = (t & 1) * 32;
  const size_t ga = ((size_t)(bm * 128 + srow)) * KDIM + scol;
  const size_t gb = ((size_t)(bn * 128 + srow)) * KDIM + scol;
  const int lane = t & 63;
  const int wid = t >> 6;
  const int wm = (wid & 1) * 64;
  const int wn = (wid >> 1) * 64;
  const int fr = lane & 15;
  const int fk = (lane >> 4) * 8;
  f32x4 acc[4][4];
#pragma unroll
  for (int a = 0; a < 4; ++a)
#pragma unroll
    for (int bq = 0; bq < 4; ++bq) acc[a][bq] = (f32x4){0.f, 0.f, 0.f, 0.f};

  for (int k0 = 0; k0 < KDIM; k0 += 64) {
    __syncthreads();
    if (flag) {
      const uint16_t* gx = (const uint16_t*)x + ga + k0;
      const uint16_t* gw = (const uint16_t*)w + gb + k0;
#pragma unroll
      for (int c = 0; c < 4; ++c) {
        *(uint4*)&sA[srow * 64 + scol + c * 8] = *(const uint4*)(gx + c * 8);
        *(uint4*)&sB[srow * 64 + scol + c * 8] = *(const uint4*)(gw + c * 8);
      }
    } else {
      const float* gx = (const float*)x + ga + k0;
      const float* gw = (const float*)w + gb + k0;
#pragma unroll
      for (int c = 0; c < 4; ++c) {
        float4 xa = *(const float4*)(gx + c * 8);
        float4 xb2 = *(const float4*)(gx + c * 8 + 4);
        uint4 pk;
        pk.x = pk2(xa.x, xa.y);
        pk.y = pk2(xa.z, xa.w);
        pk.z = pk2(xb2.x, xb2.y);
        pk.w = pk2(xb2.z, xb2.w);
        *(uint4*)&sA[srow * 64 + scol + c * 8] = pk;
        float4 wa = *(const float4*)(gw + c * 8);
        float4 wb2 = *(const float4*)(gw + c * 8 + 4);
        uint4 pw;
        pw.x = pk2(wa.x, wa.y);
        pw.y = pk2(wa.z, wa.w);
        pw.z = pk2(wb2.x, wb2.y);
        pw.w = pk2(wb2.z, wb2.w);
        *(uint4*)&sB[srow * 64 + scol + c * 8] = pw;
      }
    }
    __syncthreads();
#pragma unroll
    for (int kk = 0; kk < 64; kk += 32) {
      short8 af[4], bfr[4];
#pragma unroll
      for (int mb = 0; mb < 4; ++mb)
        af[mb] = *(const short8*)&sA[(wm + mb * 16 + fr) * 64 + kk + fk];
#pragma unroll
      for (int nb = 0; nb < 4; ++nb)
        bfr[nb] = *(const short8*)&sB[(wn + nb * 16 + fr) * 64 + kk + fk];
#pragma unroll
      for (int mb = 0; mb < 4; ++mb)
#pragma unroll
        for (int nb = 0; nb < 4; ++nb)
          acc[mb][nb] = __builtin_amdgcn_mfma_f32_16x16x32_bf16(
              af[mb], bfr[nb], acc[mb][nb], 0, 0, 0);
    }
  }
  const int rq = (lane >> 4) * 4;
#pragma unroll
  for (int nb = 0; nb < 4; ++nb) {
    const int gn = bn * 128 + wn + nb * 16 + fr;
    const float bp = b_pre_f[gn];
    const float4 u0 = *(const float4*)&W_up_s[(size_t)gn * 8];
    const float4 u1 = *(const float4*)&W_up_s[(size_t)gn * 8 + 4];
#pragma unroll
    for (int mb = 0; mb < 4; ++mb) {
#pragma unroll
      for (int r = 0; r < 4; ++r) {
        const int gm = bm * 128 + wm + mb * 16 + rq + r;
        const float4 a0 = *(const float4*)&a_o[(size_t)gm * 8];
        const float4 a1 = *(const float4*)&a_o[(size_t)gm * 8 + 4];
        float v = acc[mb][nb][r] + bp + a0.x * u0.x + a0.y * u0.y +
                  a0.z * u0.z + a0.w * u0.w + a1.x * u1.x + a1.y * u1.y +
                  a1.z * u1.z + a1.w * u1.w;
        const size_t oidx = (size_t)gm * NDIM + gn;
        if (flag) ((uint16_t*)out)[oidx] = f2b(v);
        else ((float*)out)[oidx] = v;
      }
    }
  }
}

// ---------------------------------------------------------------------------
extern "C" void kernel_launch(void* const* d_in, const int* in_sizes, int n_in,
                              void* d_out, int out_size, void* d_ws,
                              size_t ws_size, hipStream_t stream) {
  const void* x = d_in[0];
  const void* W_pre = d_in[1];
  const void* b_pre = d_in[2];
  const void* W_down = d_in[3];
  const void* W_qkv = d_in[4];
  const void* W_o = d_in[5];
  const void* W_up = d_in[6];
  const void* diag_b = d_in[7];

  char* ws = (char*)d_ws;
  int* flag_p = (int*)ws;                        // @0
  float* WcT = (float*)(ws + 256);               // [12][4096] f32
  float* qkv = (float*)(ws + 196864);            // [8192][12] f32
  float* a_o = (float*)(ws + 590080);            // [8192][8]  f32
  float* W_up_s = (float*)(ws + 852224);         // [4096][8]  f32
  float* b_pre_f = (float*)(ws + 983296);        // [4096]     f32
  uint16_t* xb = (uint16_t*)(ws + 1048576);      // [8192][4096] bf16, 64 MiB
  uint16_t* wb = (uint16_t*)(ws + 68157440);     // [4096][4096] bf16, 32 MiB
  const bool big = ws_size >= (size_t)101711872;

  k_detect<<<1, 64, 0, stream>>>((const uint16_t*)x, flag_p);
  k_prep<<<192, 256, 0, stream>>>(W_down, W_qkv, W_up, diag_b, b_pre, WcT,
                                  W_up_s, b_pre_f, flag_p);
  k_qkvconv<<<2560, 256, 0, stream>>>(x, WcT, qkv, xb, W_pre, wb,
                                      big ? 1 : 0, flag_p);
  k_attn<<<256, 256, 0, stream>>>(qkv, W_o, a_o, flag_p);
  if (big)
    k_gemm8<<<512, 512, 0, stream>>>(x, W_pre, xb, wb, a_o, W_up_s, b_pre_f,
                                     d_out, flag_p);
  else
    k_gemm_fb<<<2048, 256, 0, stream>>>(x, W_pre, a_o, W_up_s, b_pre_f, d_out,
                                        flag_p);
}